// Round 1
// baseline (2422.744 us; speedup 1.0000x reference)
//
#include <hip/hip_runtime.h>
#include <math.h>

// ============================================================================
// ConvLRUBlock on MI355X — round 1: correct FFT-free implementation.
// All DFTs folded into precomputed per-channel factors (U-hat/V-hat fwd,
// U-til/V-til inv), spectral conv via 128 explicit low modes, fuse_w folded
// into conv weights. fp32 everywhere.
// ============================================================================

constexpr int B_ = 2, L_ = 16, C = 64, H = 64, W = 128, R = 32, MH = 32;
constexpr int BL = B_ * L_;     // 32
constexpr int HW = H * W;       // 8192
constexpr int CR = C * R;       // 2048
constexpr float PI2 = 6.28318530717958647692f;

#define DEV __device__ __forceinline__

// ---------------------------------------------------------------- trig tables
__global__ __launch_bounds__(128) void k_trig(float* __restrict__ t64,
                                              float* __restrict__ t128) {
  int i = threadIdx.x;
  if (i < 64) {
    float s, c; sincosf(PI2 * (float)i / 64.0f, &s, &c);
    t64[2 * i] = c; t64[2 * i + 1] = s;
  }
  float s, c; sincosf(PI2 * (float)i / 128.0f, &s, &c);
  t128[2 * i] = c; t128[2 * i + 1] = s;
}

// ------------------------------------------------- U tables: fwd DFT, inv DFT
// Uhat[c][hp][r] = sum_h U[c][h][r] e^{-2pi i h*hp/H}
// Util[c][hp][r] = (1/H) sum_h U[c][h][r] e^{+2pi i h*hp/H}
__global__ __launch_bounds__(256) void k_utab(const float* __restrict__ Ur,
                                              const float* __restrict__ Ui,
                                              const float* __restrict__ t64,
                                              float* __restrict__ Uhat,
                                              float* __restrict__ Util) {
  int c = blockIdx.x;
  __shared__ float tt[128];
  if (threadIdx.x < 128) tt[threadIdx.x] = t64[threadIdx.x];
  __syncthreads();
  for (int t = 0; t < 8; t++) {
    int idx = t * 256 + threadIdx.x;
    int hp = idx >> 5, r = idx & 31;
    float fr = 0, fi = 0, br = 0, bi = 0;
    for (int h = 0; h < H; h++) {
      float ur = Ur[(c * H + h) * R + r], ui = Ui[(c * H + h) * R + r];
      int ph = (h * hp) & 63;
      float cs = tt[2 * ph], sn = tt[2 * ph + 1];
      fr += ur * cs + ui * sn;
      fi += ui * cs - ur * sn;
      br += ur * cs - ui * sn;
      bi += ui * cs + ur * sn;
    }
    int o = ((c * H + hp) * R + r) * 2;
    Uhat[o] = fr; Uhat[o + 1] = fi;
    Util[o] = br * (1.0f / H); Util[o + 1] = bi * (1.0f / H);
  }
}

// Vhat[c][wp][r] (fwd);  Vtil[c][r][wp] (inv, 1/W)  -- note transposed layout
__global__ __launch_bounds__(256) void k_vtab(const float* __restrict__ Vr,
                                              const float* __restrict__ Vi,
                                              const float* __restrict__ t128,
                                              float* __restrict__ Vhat,
                                              float* __restrict__ Vtil) {
  int c = blockIdx.x;
  __shared__ float tt[256];
  tt[threadIdx.x] = t128[threadIdx.x];
  __syncthreads();
  for (int t = 0; t < 16; t++) {
    int idx = t * 256 + threadIdx.x;
    int wp = idx >> 5, r = idx & 31;
    float fr = 0, fi = 0, br = 0, bi = 0;
    for (int w = 0; w < W; w++) {
      float vr = Vr[(c * W + w) * R + r], vi = Vi[(c * W + w) * R + r];
      int ph = (w * wp) & 127;
      float cs = tt[2 * ph], sn = tt[2 * ph + 1];
      fr += vr * cs + vi * sn;
      fi += vi * cs - vr * sn;
      br += vr * cs - vi * sn;
      bi += vi * cs + vr * sn;
    }
    int of = ((c * W + wp) * R + r) * 2;
    Vhat[of] = fr; Vhat[of + 1] = fi;
    int ob = ((c * R + r) * W + wp) * 2;
    Vtil[ob] = br * (1.0f / W); Vtil[ob + 1] = bi * (1.0f / W);
  }
}

// ------------------------------------------- fold fuse_w into conv weights
// Wt[(p*C+c)*9*C + tap*C + o] = sum_k fuse_w[o][p*C+k] * convw_p[k][c][tap]
__global__ __launch_bounds__(256) void k_wt(const float* __restrict__ fuse_w,
                                            const float* __restrict__ convr_w,
                                            const float* __restrict__ convi_w,
                                            float* __restrict__ Wt) {
  int pc = blockIdx.x; int p = pc >> 6, c = pc & 63;
  const float* cw = p ? convi_w : convr_w;
  for (int t = 0; t < 3; t++) {
    int idx = t * 256 + threadIdx.x;
    if (idx < 576) {
      int tap = idx >> 6, o = idx & 63;
      float s = 0;
      for (int k = 0; k < C; k++)
        s += fuse_w[o * (2 * C) + p * C + k] * cw[(k * C + c) * 9 + tap];
      Wt[((size_t)pc * 9 + tap) * C + o] = s;
    }
  }
}

__global__ __launch_bounds__(64) void k_btil(const float* __restrict__ fuse_w,
                                             const float* __restrict__ rb,
                                             const float* __restrict__ ib,
                                             const float* __restrict__ fb,
                                             float* __restrict__ btil) {
  int o = threadIdx.x;
  float s = fb[o];
  for (int k = 0; k < C; k++)
    s += fuse_w[o * (2 * C) + k] * rb[k] + fuse_w[o * (2 * C) + C + k] * ib[k];
  btil[o] = s;
}

// ------------------------------------------------------------- ctx = mean_hw
__global__ __launch_bounds__(256) void k_ctx(const float* __restrict__ x,
                                             float* __restrict__ ctx) {
  int blc = blockIdx.x;
  const float4* px = (const float4*)(x + (size_t)blc * HW);
  float s = 0;
  for (int i = threadIdx.x; i < HW / 4; i += 256) {
    float4 v = px[i];
    s += (v.x + v.y) + (v.z + v.w);
  }
  #pragma unroll
  for (int o2 = 32; o2; o2 >>= 1) s += __shfl_down(s, o2);
  __shared__ float red[4];
  if ((threadIdx.x & 63) == 0) red[threadIdx.x >> 6] = s;
  __syncthreads();
  if (threadIdx.x == 0)
    ctx[blc] = (red[0] + red[1] + red[2] + red[3]) * (1.0f / HW);
}

// --------------------------------------------- MLP forcing -> lam, gamma
__global__ __launch_bounds__(256) void k_mlp(const float* __restrict__ ctx,
                                             const float* __restrict__ w1,
                                             const float* __restrict__ b1,
                                             const float* __restrict__ w2,
                                             const float* __restrict__ b2,
                                             const float* __restrict__ fs_p,
                                             const float* __restrict__ nu_log,
                                             const float* __restrict__ th_log,
                                             float* __restrict__ lamr,
                                             float* __restrict__ lami,
                                             float* __restrict__ gam) {
  int bl = blockIdx.x;
  __shared__ float cs[C];
  __shared__ float hm[MH];
  if (threadIdx.x < C) cs[threadIdx.x] = ctx[bl * C + threadIdx.x];
  __syncthreads();
  if (threadIdx.x < MH) {
    float s = b1[threadIdx.x];
    for (int k = 0; k < C; k++) s += cs[k] * w1[k * MH + threadIdx.x];
    hm[threadIdx.x] = tanhf(s);
  }
  __syncthreads();
  float fs = fs_p[0];
  for (int t = 0; t < 8; t++) {
    int idx = t * 256 + threadIdx.x;       // (c,r) flat over CR
    float d0 = b2[idx], d1 = b2[CR + idx];
    for (int m = 0; m < MH; m++) {
      float hv = hm[m];
      d0 += hv * w2[m * (2 * CR) + idx];
      d1 += hv * w2[m * (2 * CR) + CR + idx];
    }
    float nu = expf(nu_log[idx] + fs * d0);
    float th = expf(th_log[idx] + fs * d1);
    float en = expf(-nu);
    float sn, cn; sincosf(th, &sn, &cn);
    int o = bl * CR + idx;
    lamr[o] = en * cn; lami[o] = en * sn;
    gam[o] = sqrtf(fmaxf(0.0f, 1.0f - en * en));
  }
}

// --------------------------- encode: u[b,l,c,r] and low-mode spectrum Xm
__global__ __launch_bounds__(256) void k_encode(const float* __restrict__ x,
                                                const float* __restrict__ Vhat,
                                                const float* __restrict__ Uhat,
                                                const float* __restrict__ t64,
                                                const float* __restrict__ t128,
                                                float* __restrict__ ub,
                                                float* __restrict__ Xm) {
  int blc = blockIdx.x;
  int c = blc & 63;
  __shared__ float sarr[H * R * 2];   // [h][r][2]  16KB
  __shared__ float fh[16 * W * 2];    // [i1][w][2] 16KB
  int tid = threadIdx.x;
  const float* px = x + (size_t)blc * HW;
  // s[h][r] = sum_w x[h][w] * Vhat[w][r]
  {
    int rp = tid & 15, hb = tid >> 4;
    float ar[4][4];
    #pragma unroll
    for (int q = 0; q < 4; q++)
      for (int j = 0; j < 4; j++) ar[q][j] = 0;
    const float* vp = Vhat + ((size_t)c * W * R + 2 * rp) * 2;
    for (int ww = 0; ww < W; ww++) {
      float4 vv = *(const float4*)(vp + (size_t)ww * R * 2);
      #pragma unroll
      for (int q = 0; q < 4; q++) {
        float xv = px[(hb + 16 * q) * W + ww];
        ar[q][0] += xv * vv.x; ar[q][1] += xv * vv.y;
        ar[q][2] += xv * vv.z; ar[q][3] += xv * vv.w;
      }
    }
    #pragma unroll
    for (int q = 0; q < 4; q++) {
      int h = hb + 16 * q;
      *(float4*)&sarr[(h * R + 2 * rp) * 2] =
          make_float4(ar[q][0], ar[q][1], ar[q][2], ar[q][3]);
    }
  }
  __syncthreads();
  // u[r] = sum_h Uhat[h][r] * s[h][r]   (32 threads; others proceed to Fh)
  if (tid < R) {
    int r = tid;
    float ar = 0, ai = 0;
    const float* up = Uhat + ((size_t)c * H * R + r) * 2;
    for (int h2 = 0; h2 < H; h2++) {
      float sr = sarr[(h2 * R + r) * 2], si = sarr[(h2 * R + r) * 2 + 1];
      float ur = up[(size_t)h2 * R * 2], ui2 = up[(size_t)h2 * R * 2 + 1];
      ar += ur * sr - ui2 * si;
      ai += ur * si + ui2 * sr;
    }
    ub[((size_t)blc * R + r) * 2] = ar;
    ub[((size_t)blc * R + r) * 2 + 1] = ai;
  }
  // Fh[i1][w] = sum_h x[h][w] e^{-2pi i m1 h/64}
  {
    int wq = tid & 127, ip = tid >> 7;
    for (int t = 0; t < 8; t++) {
      int i1 = t * 2 + ip;
      int m1 = i1 < 8 ? i1 : 48 + i1;
      float fr = 0, fi = 0;
      for (int h2 = 0; h2 < H; h2++) {
        float xv = px[h2 * W + wq];
        int ph = (m1 * h2) & 63;
        fr += xv * t64[2 * ph];
        fi -= xv * t64[2 * ph + 1];
      }
      fh[(i1 * W + wq) * 2] = fr; fh[(i1 * W + wq) * 2 + 1] = fi;
    }
  }
  __syncthreads();
  // Xm[i1][m2] = sum_w Fh[i1][w] e^{-2pi i m2 w/128}
  if (tid < 128) {
    int i1 = tid >> 3, m2 = tid & 7;
    float ar = 0, ai = 0;
    for (int ww = 0; ww < W; ww++) {
      float fr = fh[(i1 * W + ww) * 2], fi = fh[(i1 * W + ww) * 2 + 1];
      int ph = (m2 * ww) & 127;
      float cs = t128[2 * ph], sn = t128[2 * ph + 1];
      ar += fr * cs + fi * sn;
      ai += fi * cs - fr * sn;
    }
    Xm[((size_t)blc * 128 + tid) * 2] = ar;
    Xm[((size_t)blc * 128 + tid) * 2 + 1] = ai;
  }
}

// ------------------------------------------------- sequential scan over L=16
__global__ __launch_bounds__(256) void k_scan(const float* __restrict__ lamr,
                                              const float* __restrict__ lami,
                                              const float* __restrict__ gam,
                                              const float* __restrict__ ub,
                                              float* __restrict__ hs) {
  int idx = blockIdx.x * 256 + threadIdx.x;   // over B*C*R = 4096
  int b = idx >> 11, cr = idx & 2047;
  float hr = 0, hi = 0;
  for (int l = 0; l < L_; l++) {
    int o = (b * L_ + l) * CR + cr;
    float lr = lamr[o], li = lami[o], g = gam[o];
    float ur = ub[2 * o], ui = ub[2 * o + 1];
    float nr = lr * hr - li * hi + g * ur;
    float ni = lr * hi + li * hr + g * ui;
    hr = nr; hi = ni;
    hs[2 * o] = hr; hs[2 * o + 1] = hi;
  }
}

// ------------------------ spectral conv: mode mix (w1 low rows, w2 high rows)
__global__ __launch_bounds__(256) void k_spm(const float* __restrict__ Xm,
                                             const float* __restrict__ w1r,
                                             const float* __restrict__ w1i,
                                             const float* __restrict__ w2r,
                                             const float* __restrict__ w2i,
                                             float* __restrict__ SPm) {
  int bl = blockIdx.x;
  const float* px = Xm + (size_t)bl * C * 256;
  for (int t = 0; t < 32; t++) {
    int idx = t * 256 + threadIdx.x;      // o*128 + mode
    int o = idx >> 7, mode = idx & 127;
    int i1 = mode >> 3, m2 = mode & 7;
    const float* wr; const float* wi; int ii;
    if (i1 < 8) { wr = w1r; wi = w1i; ii = i1; }
    else        { wr = w2r; wi = w2i; ii = i1 - 8; }
    float ar = 0, ai = 0;
    for (int cc = 0; cc < C; cc++) {
      float xr = px[(cc * 128 + mode) * 2], xi = px[(cc * 128 + mode) * 2 + 1];
      float wrr = wr[((size_t)(o * C + cc) * 8 + ii) * 8 + m2];
      float wii = wi[((size_t)(o * C + cc) * 8 + ii) * 8 + m2];
      ar += xr * wrr - xi * wii;
      ai += xr * wii + xi * wrr;
    }
    SPm[((size_t)bl * C * 128 + idx) * 2] = ar * (1.0f / HW);
    SPm[((size_t)bl * C * 128 + idx) * 2 + 1] = ai * (1.0f / HW);
  }
}

// ---------------- Q[blo][h][m2] = sum_i1 SPm[blo][i1][m2] e^{+2pi i m1 h/64}
__global__ __launch_bounds__(256) void k_q(const float* __restrict__ SPm,
                                           const float* __restrict__ t64,
                                           float* __restrict__ Qb) {
  int blo = blockIdx.x;                 // bl*64 + o
  __shared__ float sp[256];
  int tid = threadIdx.x;
  sp[tid] = SPm[(size_t)blo * 256 + tid];
  __syncthreads();
  for (int t = 0; t < 2; t++) {
    int idx = t * 256 + tid;
    int h = idx >> 3, m2 = idx & 7;
    float ar = 0, ai = 0;
    #pragma unroll
    for (int i1 = 0; i1 < 16; i1++) {
      int m1 = i1 < 8 ? i1 : 48 + i1;
      int ph = (m1 * h) & 63;
      float cs = t64[2 * ph], sn = t64[2 * ph + 1];
      float sr = sp[(i1 * 8 + m2) * 2], si = sp[(i1 * 8 + m2) * 2 + 1];
      ar += sr * cs - si * sn;
      ai += sr * sn + si * cs;
    }
    Qb[((size_t)blo * H * 8 + idx) * 2] = ar;
    Qb[((size_t)blo * H * 8 + idx) * 2 + 1] = ai;
  }
}

// ------------- decode low-rank + channel proj + spectral add + projb -> zbuf
// grid (32 bl, 8 h-tiles, 4 w-tiles), 512 threads.
// Output tile: 64 o x 8 h x 32 w (complex). c processed in chunks of 8.
__global__ __launch_bounds__(512) void k_decode(
    const float* __restrict__ hs, const float* __restrict__ Util,
    const float* __restrict__ Vtil, const float* __restrict__ pwr,
    const float* __restrict__ pwi, const float* __restrict__ pbr,
    const float* __restrict__ pbi, const float* __restrict__ Qb,
    const float* __restrict__ t128, float* __restrict__ zre,
    float* __restrict__ zim) {
  int bl = blockIdx.x;
  int h0 = blockIdx.y * 8;
  int w0 = blockIdx.z * 32;
  __shared__ float g[8][8][R][2];        // [ci][h][r]  16KB
  __shared__ float ybuf[8][8][34][2];    // [ci][h][w(+pad)] 17KB
  int tid = threadIdx.x;
  int ob = __builtin_amdgcn_readfirstlane(tid >> 6) * 8;
  int lane = tid & 63;
  int lh = lane >> 3;
  int lw = lane & 7;
  float zr[8][4], zi[8][4];
  #pragma unroll
  for (int a = 0; a < 8; a++)
    for (int j = 0; j < 4; j++) { zr[a][j] = 0; zi[a][j] = 0; }
  for (int chunk = 0; chunk < 8; chunk++) {
    int c0 = chunk * 8;
    __syncthreads();
    // g = hs * Util
    for (int t = 0; t < 4; t++) {
      int idx = t * 512 + tid;
      int ci = idx >> 8, hh = (idx >> 5) & 7, r = idx & 31;
      int c = c0 + ci;
      const float* hp = hs + ((size_t)bl * C + c) * R * 2 + r * 2;
      const float* up = Util + (((size_t)c * H + h0 + hh) * R + r) * 2;
      float hr = hp[0], hi = hp[1], ur = up[0], ui = up[1];
      g[ci][hh][r][0] = hr * ur - hi * ui;
      g[ci][hh][r][1] = hr * ui + hi * ur;
    }
    __syncthreads();
    // y = sum_r g * Vtil
    for (int t = 0; t < 4; t++) {
      int idx = t * 512 + tid;
      int ci = idx >> 8, hh = (idx >> 5) & 7, w = idx & 31;
      int c = c0 + ci;
      float ar = 0, ai = 0;
      const float* vp = Vtil + ((size_t)c * R * W + w0 + w) * 2;
      #pragma unroll 8
      for (int r = 0; r < R; r++) {
        float vr = vp[(size_t)r * W * 2], vi = vp[(size_t)r * W * 2 + 1];
        float gr = g[ci][hh][r][0], gi = g[ci][hh][r][1];
        ar += gr * vr - gi * vi;
        ai += gr * vi + gi * vr;
      }
      ybuf[ci][hh][w][0] = ar; ybuf[ci][hh][w][1] = ai;
    }
    __syncthreads();
    // z += projW * y  (thread: 8 o x 4 w at its lh)
    #pragma unroll
    for (int ci = 0; ci < 8; ci++) {
      int c = c0 + ci;
      float4 y01 = *(const float4*)&ybuf[ci][lh][4 * lw][0];
      float4 y23 = *(const float4*)&ybuf[ci][lh][4 * lw + 2][0];
      float yrv[4] = {y01.x, y01.z, y23.x, y23.z};
      float yiv[4] = {y01.y, y01.w, y23.y, y23.w};
      #pragma unroll
      for (int a = 0; a < 8; a++) {
        float wr = pwr[(ob + a) * C + c], wi = pwi[(ob + a) * C + c];
        #pragma unroll
        for (int j = 0; j < 4; j++) {
          zr[a][j] += wr * yrv[j] - wi * yiv[j];
          zi[a][j] += wr * yiv[j] + wi * yrv[j];
        }
      }
    }
  }
  // spectral conv (Q) + projb + store
  int hh = h0 + lh;
  #pragma unroll
  for (int a = 0; a < 8; a++) {
    int o = ob + a;
    const float* qp = Qb + ((size_t)(bl * C + o) * H + hh) * 8 * 2;
    #pragma unroll
    for (int m2 = 0; m2 < 8; m2++) {
      float qr2 = qp[2 * m2], qi2 = qp[2 * m2 + 1];
      #pragma unroll
      for (int j = 0; j < 4; j++) {
        int w = w0 + 4 * lw + j;
        int ph = (m2 * w) & 127;
        float cs = t128[2 * ph], sn = t128[2 * ph + 1];
        zr[a][j] += qr2 * cs - qi2 * sn;
        zi[a][j] += qr2 * sn + qi2 * cs;
      }
    }
    if (hh == 0 && w0 == 0 && lw == 0) {
      zr[a][0] += pbr[o]; zi[a][0] += pbi[o];
    }
    size_t off = ((size_t)(bl * C + o) * H + hh) * W + w0 + 4 * lw;
    *(float4*)&zre[off] = make_float4(zr[a][0], zr[a][1], zr[a][2], zr[a][3]);
    *(float4*)&zim[off] = make_float4(zi[a][0], zi[a][1], zi[a][2], zi[a][3]);
  }
}

// ------------------------- 3x3 conv (2 planes, folded weights) -> out_pre
// grid BL*H (one output row), 256 thr; wave owns 16 o's, lane owns 2 w's.
__global__ __launch_bounds__(256) void k_conv(const float* __restrict__ zre,
                                              const float* __restrict__ zim,
                                              const float* __restrict__ Wt,
                                              const float* __restrict__ btil,
                                              float* __restrict__ outp) {
  int bl = blockIdx.x >> 6;
  int h = blockIdx.x & 63;
  int tid = threadIdx.x;
  int ob = __builtin_amdgcn_readfirstlane(tid >> 6) * 16;
  int lane = tid & 63;
  int w0 = lane * 2;
  __shared__ float tile[3][132];
  float acc0[16], acc1[16];
  #pragma unroll
  for (int i = 0; i < 16; i++) { float b = btil[ob + i]; acc0[i] = b; acc1[i] = b; }
  for (int p = 0; p < 2; p++) {
    const float* zp = p ? zim : zre;
    for (int c = 0; c < C; c++) {
      __syncthreads();
      for (int i = tid; i < 396; i += 256) {
        int rr = i / 132, col = i % 132;
        int hr = h - 1 + rr, wc = col - 1;
        float v = 0;
        if (hr >= 0 && hr < H && wc >= 0 && wc < W)
          v = zp[((size_t)(bl * C + c) * H + hr) * W + wc];
        tile[rr][col] = v;
      }
      __syncthreads();
      const float* wp = Wt + (size_t)(p * C + c) * 9 * C + ob;
      #pragma unroll
      for (int kh = 0; kh < 3; kh++) {
        float a = tile[kh][w0], b = tile[kh][w0 + 1];
        float c2 = tile[kh][w0 + 2], d = tile[kh][w0 + 3];
        const float* wk = wp + kh * 3 * C;
        #pragma unroll
        for (int oo = 0; oo < 16; oo++) {
          float wa = wk[oo], wb = wk[C + oo], wc2 = wk[2 * C + oo];
          acc0[oo] += wa * a + wb * b + wc2 * c2;
          acc1[oo] += wa * b + wb * c2 + wc2 * d;
        }
      }
    }
  }
  #pragma unroll
  for (int oo = 0; oo < 16; oo++) {
    size_t off = ((size_t)(bl * C + ob + oo) * H + h) * W + w0;
    *(float2*)&outp[off] = make_float2(acc0[oo], acc1[oo]);
  }
}

// ------------------------------------------------------------- LN statistics
__global__ __launch_bounds__(256) void k_lnstats(const float* __restrict__ outp,
                                                 float* __restrict__ mu,
                                                 float* __restrict__ rstd) {
  int i = blockIdx.x;
  const float4* p = (const float4*)(outp + (size_t)i * HW);
  float s = 0, q = 0;
  for (int t = threadIdx.x; t < HW / 4; t += 256) {
    float4 v = p[t];
    s += (v.x + v.y) + (v.z + v.w);
    q += (v.x * v.x + v.y * v.y) + (v.z * v.z + v.w * v.w);
  }
  #pragma unroll
  for (int o2 = 32; o2; o2 >>= 1) { s += __shfl_down(s, o2); q += __shfl_down(q, o2); }
  __shared__ float rs[4], rq[4];
  if ((threadIdx.x & 63) == 0) { rs[threadIdx.x >> 6] = s; rq[threadIdx.x >> 6] = q; }
  __syncthreads();
  if (threadIdx.x == 0) {
    float S = rs[0] + rs[1] + rs[2] + rs[3];
    float Q = rq[0] + rq[1] + rq[2] + rq[3];
    float m = S * (1.0f / HW);
    float var = Q * (1.0f / HW) - m * m;
    mu[i] = m; rstd[i] = rsqrtf(var + 1e-5f);
  }
}

// -------------------------------- gate matmul + LN apply + residual (inplace)
__global__ __launch_bounds__(256) void k_final(const float* __restrict__ x,
                                               const float* __restrict__ gw,
                                               const float* __restrict__ gb,
                                               const float* __restrict__ mu,
                                               const float* __restrict__ rstd,
                                               const float* __restrict__ lnw,
                                               const float* __restrict__ lnb,
                                               float* __restrict__ outp) {
  int bl = blockIdx.x >> 6, h = blockIdx.x & 63;
  int tid = threadIdx.x;
  __shared__ float xs[C * W];   // 32KB
  for (int i = tid; i < C * W; i += 256) {
    int c = i >> 7, w = i & 127;
    xs[i] = x[((size_t)(bl * C + c) * H + h) * W + w];
  }
  __syncthreads();
  int w = tid & 127;
  int oh = __builtin_amdgcn_readfirstlane(tid >> 7);  // wave-uniform 0/1
  float glin[32];
  #pragma unroll
  for (int i = 0; i < 32; i++) glin[i] = gb[oh * 32 + i];
  for (int cc = 0; cc < C; cc++) {
    float xv = xs[cc * W + w];
    const float* gwp = gw + (size_t)(oh * 32) * C + cc;
    #pragma unroll
    for (int i = 0; i < 32; i++) glin[i] += gwp[(size_t)i * C] * xv;
  }
  float lw = lnw[h * W + w], lb = lnb[h * W + w];
  #pragma unroll
  for (int i = 0; i < 32; i++) {
    int o = oh * 32 + i;
    size_t off = ((size_t)(bl * C + o) * H + h) * W + w;
    float m = mu[bl * C + o], rs = rstd[bl * C + o];
    float op = outp[off];
    float nrm = (op - m) * rs * lw + lb;
    float sg = 1.0f / (1.0f + expf(-glin[i]));
    outp[off] = xs[o * W + w] + sg * nrm;
  }
}

// ============================================================================
extern "C" void kernel_launch(void* const* d_in, const int* in_sizes, int n_in,
                              void* d_out, int out_size, void* d_ws,
                              size_t ws_size, hipStream_t stream) {
  const float* x       = (const float*)d_in[0];
  const float* nu_log  = (const float*)d_in[1];
  const float* th_log  = (const float*)d_in[2];
  const float* mlp_w1  = (const float*)d_in[3];
  const float* mlp_b1  = (const float*)d_in[4];
  const float* mlp_w2  = (const float*)d_in[5];
  const float* mlp_b2  = (const float*)d_in[6];
  const float* fscale  = (const float*)d_in[7];
  const float* U_r     = (const float*)d_in[8];
  const float* U_i     = (const float*)d_in[9];
  const float* V_r     = (const float*)d_in[10];
  const float* V_i     = (const float*)d_in[11];
  const float* pW_r    = (const float*)d_in[12];
  const float* pW_i    = (const float*)d_in[13];
  const float* pb_r    = (const float*)d_in[14];
  const float* pb_i    = (const float*)d_in[15];
  const float* swr1    = (const float*)d_in[16];
  const float* swi1    = (const float*)d_in[17];
  const float* swr2    = (const float*)d_in[18];
  const float* swi2    = (const float*)d_in[19];
  const float* convr_w = (const float*)d_in[20];
  const float* convr_b = (const float*)d_in[21];
  const float* convi_w = (const float*)d_in[22];
  const float* convi_b = (const float*)d_in[23];
  const float* fuse_w  = (const float*)d_in[24];
  const float* fuse_b  = (const float*)d_in[25];
  const float* gate_w  = (const float*)d_in[26];
  const float* gate_b  = (const float*)d_in[27];
  const float* ln_w    = (const float*)d_in[28];
  const float* ln_b    = (const float*)d_in[29];
  float* outp = (float*)d_out;

  char* wsb = (char*)d_ws;
  size_t off = 0;
  auto alloc = [&](size_t nfloats) -> float* {
    float* p = (float*)(wsb + off);
    off += ((nfloats * 4 + 255) / 256) * 256;
    return p;
  };
  float* trig64  = alloc(128);
  float* trig128 = alloc(256);
  float* Uhat = alloc((size_t)C * H * R * 2);
  float* Util = alloc((size_t)C * H * R * 2);
  float* Vhat = alloc((size_t)C * W * R * 2);
  float* Vtil = alloc((size_t)C * W * R * 2);
  float* Wt   = alloc((size_t)2 * C * 9 * C);
  float* btil = alloc(C);
  float* ctx  = alloc(BL * C);
  float* lamr = alloc(BL * CR);
  float* lami = alloc(BL * CR);
  float* gam  = alloc(BL * CR);
  float* ub   = alloc((size_t)BL * CR * 2);
  float* hs   = alloc((size_t)BL * CR * 2);
  float* Xm   = alloc((size_t)BL * C * 128 * 2);
  float* SPm  = alloc((size_t)BL * C * 128 * 2);
  float* Qb   = alloc((size_t)BL * C * H * 8 * 2);
  float* zre  = alloc((size_t)BL * C * HW);
  float* zim  = alloc((size_t)BL * C * HW);
  float* mu   = alloc(BL * C);
  float* rstd = alloc(BL * C);

  k_trig<<<1, 128, 0, stream>>>(trig64, trig128);
  k_utab<<<C, 256, 0, stream>>>(U_r, U_i, trig64, Uhat, Util);
  k_vtab<<<C, 256, 0, stream>>>(V_r, V_i, trig128, Vhat, Vtil);
  k_wt<<<2 * C, 256, 0, stream>>>(fuse_w, convr_w, convi_w, Wt);
  k_btil<<<1, 64, 0, stream>>>(fuse_w, convr_b, convi_b, fuse_b, btil);
  k_ctx<<<BL * C, 256, 0, stream>>>(x, ctx);
  k_mlp<<<BL, 256, 0, stream>>>(ctx, mlp_w1, mlp_b1, mlp_w2, mlp_b2, fscale,
                                nu_log, th_log, lamr, lami, gam);
  k_encode<<<BL * C, 256, 0, stream>>>(x, Vhat, Uhat, trig64, trig128, ub, Xm);
  k_scan<<<16, 256, 0, stream>>>(lamr, lami, gam, ub, hs);
  k_spm<<<BL, 256, 0, stream>>>(Xm, swr1, swi1, swr2, swi2, SPm);
  k_q<<<BL * C, 256, 0, stream>>>(SPm, trig64, Qb);
  k_decode<<<dim3(BL, 8, 4), 512, 0, stream>>>(hs, Util, Vtil, pW_r, pW_i,
                                               pb_r, pb_i, Qb, trig128, zre, zim);
  k_conv<<<BL * H, 256, 0, stream>>>(zre, zim, Wt, btil, outp);
  k_lnstats<<<BL * C, 256, 0, stream>>>(outp, mu, rstd);
  k_final<<<BL * H, 256, 0, stream>>>(x, gate_w, gate_b, mu, rstd, ln_w, ln_b,
                                      outp);
}

// Round 2
// 1903.989 us; speedup vs baseline: 1.2725x; 1.2725x over previous
//
#include <hip/hip_runtime.h>
#include <math.h>

// ============================================================================
// ConvLRUBlock on MI355X — round 2: MFMA bf16 implicit-GEMM conv.
// DFTs folded into precomputed per-channel factors; z written bf16 pixel-major
// [p][bl][h][w][c]; conv = implicit GEMM M=64(o) N=128(w/row) K=1152 via
// v_mfma_f32_16x16x32_bf16 with XOR-swizzled LDS staging.
// ============================================================================

constexpr int B_ = 2, L_ = 16, C = 64, H = 64, W = 128, R = 32, MH = 32;
constexpr int BL = B_ * L_;     // 32
constexpr int HW = H * W;       // 8192
constexpr int CR = C * R;       // 2048
constexpr float PI2 = 6.28318530717958647692f;

#define DEV __device__ __forceinline__

typedef __attribute__((ext_vector_type(8))) short bf16x8;
typedef __attribute__((ext_vector_type(4))) float f32x4;

static DEV unsigned short f2bf(float f) {
  unsigned u = __float_as_uint(f);
  u = u + 0x7fffu + ((u >> 16) & 1u);
  return (unsigned short)(u >> 16);
}

// ---------------------------------------------------------------- trig tables
__global__ __launch_bounds__(128) void k_trig(float* __restrict__ t64,
                                              float* __restrict__ t128) {
  int i = threadIdx.x;
  if (i < 64) {
    float s, c; sincosf(PI2 * (float)i / 64.0f, &s, &c);
    t64[2 * i] = c; t64[2 * i + 1] = s;
  }
  float s, c; sincosf(PI2 * (float)i / 128.0f, &s, &c);
  t128[2 * i] = c; t128[2 * i + 1] = s;
}

// ------------------------------------------------- U tables: fwd DFT, inv DFT
__global__ __launch_bounds__(256) void k_utab(const float* __restrict__ Ur,
                                              const float* __restrict__ Ui,
                                              const float* __restrict__ t64,
                                              float* __restrict__ Uhat,
                                              float* __restrict__ Util) {
  int c = blockIdx.x;
  __shared__ float tt[128];
  if (threadIdx.x < 128) tt[threadIdx.x] = t64[threadIdx.x];
  __syncthreads();
  for (int t = 0; t < 8; t++) {
    int idx = t * 256 + threadIdx.x;
    int hp = idx >> 5, r = idx & 31;
    float fr = 0, fi = 0, br = 0, bi = 0;
    for (int h = 0; h < H; h++) {
      float ur = Ur[(c * H + h) * R + r], ui = Ui[(c * H + h) * R + r];
      int ph = (h * hp) & 63;
      float cs = tt[2 * ph], sn = tt[2 * ph + 1];
      fr += ur * cs + ui * sn;
      fi += ui * cs - ur * sn;
      br += ur * cs - ui * sn;
      bi += ui * cs + ur * sn;
    }
    int o = ((c * H + hp) * R + r) * 2;
    Uhat[o] = fr; Uhat[o + 1] = fi;
    Util[o] = br * (1.0f / H); Util[o + 1] = bi * (1.0f / H);
  }
}

// Vhat[c][wp][r] (fwd);  Vtil[c][r][wp] (inv, 1/W)  -- note transposed layout
__global__ __launch_bounds__(256) void k_vtab(const float* __restrict__ Vr,
                                              const float* __restrict__ Vi,
                                              const float* __restrict__ t128,
                                              float* __restrict__ Vhat,
                                              float* __restrict__ Vtil) {
  int c = blockIdx.x;
  __shared__ float tt[256];
  tt[threadIdx.x] = t128[threadIdx.x];
  __syncthreads();
  for (int t = 0; t < 16; t++) {
    int idx = t * 256 + threadIdx.x;
    int wp = idx >> 5, r = idx & 31;
    float fr = 0, fi = 0, br = 0, bi = 0;
    for (int w = 0; w < W; w++) {
      float vr = Vr[(c * W + w) * R + r], vi = Vi[(c * W + w) * R + r];
      int ph = (w * wp) & 127;
      float cs = tt[2 * ph], sn = tt[2 * ph + 1];
      fr += vr * cs + vi * sn;
      fi += vi * cs - vr * sn;
      br += vr * cs - vi * sn;
      bi += vi * cs + vr * sn;
    }
    int of = ((c * W + wp) * R + r) * 2;
    Vhat[of] = fr; Vhat[of + 1] = fi;
    int ob = ((c * R + r) * W + wp) * 2;
    Vtil[ob] = br * (1.0f / W); Vtil[ob + 1] = bi * (1.0f / W);
  }
}

// ---------------- fold fuse_w into conv weights, MFMA A-frag order, bf16
// Wb[p][tap][o][c] = sum_k fuse_w[o][p*C+k] * convw_p[k][c][tap]
__global__ __launch_bounds__(256) void k_wb(const float* __restrict__ fuse_w,
                                            const float* __restrict__ convr_w,
                                            const float* __restrict__ convi_w,
                                            unsigned short* __restrict__ Wb) {
  int po = blockIdx.x; int p = po >> 6, o = po & 63;
  const float* cw = p ? convi_w : convr_w;
  __shared__ float fw[64];
  if (threadIdx.x < 64) fw[threadIdx.x] = fuse_w[o * (2 * C) + p * C + threadIdx.x];
  __syncthreads();
  for (int t = 0; t < 3; t++) {
    int idx = t * 256 + threadIdx.x;      // tap*64 + c
    if (idx < 576) {
      int tap = idx >> 6, c = idx & 63;
      float s = 0;
      for (int k = 0; k < C; k++) s += fw[k] * cw[(k * C + c) * 9 + tap];
      Wb[((size_t)(p * 9 + tap) * C + o) * C + c] = f2bf(s);
    }
  }
}

__global__ __launch_bounds__(64) void k_btil(const float* __restrict__ fuse_w,
                                             const float* __restrict__ rb,
                                             const float* __restrict__ ib,
                                             const float* __restrict__ fb,
                                             float* __restrict__ btil) {
  int o = threadIdx.x;
  float s = fb[o];
  for (int k = 0; k < C; k++)
    s += fuse_w[o * (2 * C) + k] * rb[k] + fuse_w[o * (2 * C) + C + k] * ib[k];
  btil[o] = s;
}

// ------------------------------------------------------------- ctx = mean_hw
__global__ __launch_bounds__(256) void k_ctx(const float* __restrict__ x,
                                             float* __restrict__ ctx) {
  int blc = blockIdx.x;
  const float4* px = (const float4*)(x + (size_t)blc * HW);
  float s = 0;
  for (int i = threadIdx.x; i < HW / 4; i += 256) {
    float4 v = px[i];
    s += (v.x + v.y) + (v.z + v.w);
  }
  #pragma unroll
  for (int o2 = 32; o2; o2 >>= 1) s += __shfl_down(s, o2);
  __shared__ float red[4];
  if ((threadIdx.x & 63) == 0) red[threadIdx.x >> 6] = s;
  __syncthreads();
  if (threadIdx.x == 0)
    ctx[blc] = (red[0] + red[1] + red[2] + red[3]) * (1.0f / HW);
}

// --------------------------------------------- MLP forcing -> lam, gamma
__global__ __launch_bounds__(256) void k_mlp(const float* __restrict__ ctx,
                                             const float* __restrict__ w1,
                                             const float* __restrict__ b1,
                                             const float* __restrict__ w2,
                                             const float* __restrict__ b2,
                                             const float* __restrict__ fs_p,
                                             const float* __restrict__ nu_log,
                                             const float* __restrict__ th_log,
                                             float* __restrict__ lamr,
                                             float* __restrict__ lami,
                                             float* __restrict__ gam) {
  int bl = blockIdx.x;
  __shared__ float cs[C];
  __shared__ float hm[MH];
  if (threadIdx.x < C) cs[threadIdx.x] = ctx[bl * C + threadIdx.x];
  __syncthreads();
  if (threadIdx.x < MH) {
    float s = b1[threadIdx.x];
    for (int k = 0; k < C; k++) s += cs[k] * w1[k * MH + threadIdx.x];
    hm[threadIdx.x] = tanhf(s);
  }
  __syncthreads();
  float fs = fs_p[0];
  for (int t = 0; t < 8; t++) {
    int idx = t * 256 + threadIdx.x;       // (c,r) flat over CR
    float d0 = b2[idx], d1 = b2[CR + idx];
    for (int m = 0; m < MH; m++) {
      float hv = hm[m];
      d0 += hv * w2[m * (2 * CR) + idx];
      d1 += hv * w2[m * (2 * CR) + CR + idx];
    }
    float nu = expf(nu_log[idx] + fs * d0);
    float th = expf(th_log[idx] + fs * d1);
    float en = expf(-nu);
    float sn, cn; sincosf(th, &sn, &cn);
    int o = bl * CR + idx;
    lamr[o] = en * cn; lami[o] = en * sn;
    gam[o] = sqrtf(fmaxf(0.0f, 1.0f - en * en));
  }
}

// --------------------------- encode: u[b,l,c,r] and low-mode spectrum Xm
__global__ __launch_bounds__(256) void k_encode(const float* __restrict__ x,
                                                const float* __restrict__ Vhat,
                                                const float* __restrict__ Uhat,
                                                const float* __restrict__ t64,
                                                const float* __restrict__ t128,
                                                float* __restrict__ ub,
                                                float* __restrict__ Xm) {
  int blc = blockIdx.x;
  int c = blc & 63;
  __shared__ float sarr[H * R * 2];   // [h][r][2]  16KB
  __shared__ float fh[16 * W * 2];    // [i1][w][2] 16KB
  int tid = threadIdx.x;
  const float* px = x + (size_t)blc * HW;
  // s[h][r] = sum_w x[h][w] * Vhat[w][r]
  {
    int rp = tid & 15, hb = tid >> 4;
    float ar[4][4];
    #pragma unroll
    for (int q = 0; q < 4; q++)
      for (int j = 0; j < 4; j++) ar[q][j] = 0;
    const float* vp = Vhat + ((size_t)c * W * R + 2 * rp) * 2;
    for (int ww = 0; ww < W; ww++) {
      float4 vv = *(const float4*)(vp + (size_t)ww * R * 2);
      #pragma unroll
      for (int q = 0; q < 4; q++) {
        float xv = px[(hb + 16 * q) * W + ww];
        ar[q][0] += xv * vv.x; ar[q][1] += xv * vv.y;
        ar[q][2] += xv * vv.z; ar[q][3] += xv * vv.w;
      }
    }
    #pragma unroll
    for (int q = 0; q < 4; q++) {
      int h = hb + 16 * q;
      *(float4*)&sarr[(h * R + 2 * rp) * 2] =
          make_float4(ar[q][0], ar[q][1], ar[q][2], ar[q][3]);
    }
  }
  __syncthreads();
  // u[r] = sum_h Uhat[h][r] * s[h][r]
  if (tid < R) {
    int r = tid;
    float ar = 0, ai = 0;
    const float* up = Uhat + ((size_t)c * H * R + r) * 2;
    for (int h2 = 0; h2 < H; h2++) {
      float sr = sarr[(h2 * R + r) * 2], si = sarr[(h2 * R + r) * 2 + 1];
      float ur = up[(size_t)h2 * R * 2], ui2 = up[(size_t)h2 * R * 2 + 1];
      ar += ur * sr - ui2 * si;
      ai += ur * si + ui2 * sr;
    }
    ub[((size_t)blc * R + r) * 2] = ar;
    ub[((size_t)blc * R + r) * 2 + 1] = ai;
  }
  // Fh[i1][w] = sum_h x[h][w] e^{-2pi i m1 h/64}
  {
    int wq = tid & 127, ip = tid >> 7;
    for (int t = 0; t < 8; t++) {
      int i1 = t * 2 + ip;
      int m1 = i1 < 8 ? i1 : 48 + i1;
      float fr = 0, fi = 0;
      for (int h2 = 0; h2 < H; h2++) {
        float xv = px[h2 * W + wq];
        int ph = (m1 * h2) & 63;
        fr += xv * t64[2 * ph];
        fi -= xv * t64[2 * ph + 1];
      }
      fh[(i1 * W + wq) * 2] = fr; fh[(i1 * W + wq) * 2 + 1] = fi;
    }
  }
  __syncthreads();
  // Xm[i1][m2] = sum_w Fh[i1][w] e^{-2pi i m2 w/128}
  if (tid < 128) {
    int i1 = tid >> 3, m2 = tid & 7;
    float ar = 0, ai = 0;
    for (int ww = 0; ww < W; ww++) {
      float fr = fh[(i1 * W + ww) * 2], fi = fh[(i1 * W + ww) * 2 + 1];
      int ph = (m2 * ww) & 127;
      float cs = t128[2 * ph], sn = t128[2 * ph + 1];
      ar += fr * cs + fi * sn;
      ai += fi * cs - fr * sn;
    }
    Xm[((size_t)blc * 128 + tid) * 2] = ar;
    Xm[((size_t)blc * 128 + tid) * 2 + 1] = ai;
  }
}

// ------------------------------------------------- sequential scan over L=16
__global__ __launch_bounds__(256) void k_scan(const float* __restrict__ lamr,
                                              const float* __restrict__ lami,
                                              const float* __restrict__ gam,
                                              const float* __restrict__ ub,
                                              float* __restrict__ hs) {
  int idx = blockIdx.x * 256 + threadIdx.x;   // over B*C*R = 4096
  int b = idx >> 11, cr = idx & 2047;
  float hr = 0, hi = 0;
  for (int l = 0; l < L_; l++) {
    int o = (b * L_ + l) * CR + cr;
    float lr = lamr[o], li = lami[o], g = gam[o];
    float ur = ub[2 * o], ui = ub[2 * o + 1];
    float nr = lr * hr - li * hi + g * ur;
    float ni = lr * hi + li * hr + g * ui;
    hr = nr; hi = ni;
    hs[2 * o] = hr; hs[2 * o + 1] = hi;
  }
}

// ------------------------ spectral conv: mode mix (w1 low rows, w2 high rows)
__global__ __launch_bounds__(256) void k_spm(const float* __restrict__ Xm,
                                             const float* __restrict__ w1r,
                                             const float* __restrict__ w1i,
                                             const float* __restrict__ w2r,
                                             const float* __restrict__ w2i,
                                             float* __restrict__ SPm) {
  int bl = blockIdx.x;
  int o0 = blockIdx.y * 8;
  const float* px = Xm + (size_t)bl * C * 256;
  for (int t = 0; t < 4; t++) {
    int idx = t * 256 + threadIdx.x;      // local o*128 + mode, 1024 items
    int o = o0 + (idx >> 7), mode = idx & 127;
    int i1 = mode >> 3, m2 = mode & 7;
    const float* wr; const float* wi; int ii;
    if (i1 < 8) { wr = w1r; wi = w1i; ii = i1; }
    else        { wr = w2r; wi = w2i; ii = i1 - 8; }
    float ar = 0, ai = 0;
    for (int cc = 0; cc < C; cc++) {
      float xr = px[(cc * 128 + mode) * 2], xi = px[(cc * 128 + mode) * 2 + 1];
      float wrr = wr[((size_t)(o * C + cc) * 8 + ii) * 8 + m2];
      float wii = wi[((size_t)(o * C + cc) * 8 + ii) * 8 + m2];
      ar += xr * wrr - xi * wii;
      ai += xr * wii + xi * wrr;
    }
    size_t oo = (size_t)bl * C * 128 + (size_t)o * 128 + mode;
    SPm[oo * 2] = ar * (1.0f / HW);
    SPm[oo * 2 + 1] = ai * (1.0f / HW);
  }
}

// ---------------- Q[blo][h][m2] = sum_i1 SPm[blo][i1][m2] e^{+2pi i m1 h/64}
__global__ __launch_bounds__(256) void k_q(const float* __restrict__ SPm,
                                           const float* __restrict__ t64,
                                           float* __restrict__ Qb) {
  int blo = blockIdx.x;                 // bl*64 + o
  __shared__ float sp[256];
  int tid = threadIdx.x;
  sp[tid] = SPm[(size_t)blo * 256 + tid];
  __syncthreads();
  for (int t = 0; t < 2; t++) {
    int idx = t * 256 + tid;
    int h = idx >> 3, m2 = idx & 7;
    float ar = 0, ai = 0;
    #pragma unroll
    for (int i1 = 0; i1 < 16; i1++) {
      int m1 = i1 < 8 ? i1 : 48 + i1;
      int ph = (m1 * h) & 63;
      float cs = t64[2 * ph], sn = t64[2 * ph + 1];
      float sr = sp[(i1 * 8 + m2) * 2], si = sp[(i1 * 8 + m2) * 2 + 1];
      ar += sr * cs - si * sn;
      ai += sr * sn + si * cs;
    }
    Qb[((size_t)blo * H * 8 + idx) * 2] = ar;
    Qb[((size_t)blo * H * 8 + idx) * 2 + 1] = ai;
  }
}

// ------------- decode low-rank + channel proj + spectral add + projb -> Z bf16
// grid (32 bl, 8 h-tiles, 4 w-tiles), 512 threads.
// Z layout: [p][bl][h][w][c] bf16 (pixel-major, c contiguous) for MFMA conv.
__global__ __launch_bounds__(512) void k_decode(
    const float* __restrict__ hs, const float* __restrict__ Util,
    const float* __restrict__ Vtil, const float* __restrict__ pwr,
    const float* __restrict__ pwi, const float* __restrict__ pbr,
    const float* __restrict__ pbi, const float* __restrict__ Qb,
    const float* __restrict__ t128, unsigned short* __restrict__ Zr,
    unsigned short* __restrict__ Zi) {
  int bl = blockIdx.x;
  int h0 = blockIdx.y * 8;
  int w0 = blockIdx.z * 32;
  __shared__ float g[8][8][R][2];        // [ci][h][r]  16KB
  __shared__ float ybuf[8][8][34][2];    // [ci][h][w(+pad)] 17KB
  int tid = threadIdx.x;
  int ob = __builtin_amdgcn_readfirstlane(tid >> 6) * 8;
  int lane = tid & 63;
  int lh = lane >> 3;
  int lw = lane & 7;
  float zr[8][4], zi[8][4];
  #pragma unroll
  for (int a = 0; a < 8; a++)
    for (int j = 0; j < 4; j++) { zr[a][j] = 0; zi[a][j] = 0; }
  for (int chunk = 0; chunk < 8; chunk++) {
    int c0 = chunk * 8;
    __syncthreads();
    // g = hs * Util
    for (int t = 0; t < 4; t++) {
      int idx = t * 512 + tid;
      int ci = idx >> 8, hh = (idx >> 5) & 7, r = idx & 31;
      int c = c0 + ci;
      const float* hp = hs + ((size_t)bl * C + c) * R * 2 + r * 2;
      const float* up = Util + (((size_t)c * H + h0 + hh) * R + r) * 2;
      float hr = hp[0], hi = hp[1], ur = up[0], ui = up[1];
      g[ci][hh][r][0] = hr * ur - hi * ui;
      g[ci][hh][r][1] = hr * ui + hi * ur;
    }
    __syncthreads();
    // y = sum_r g * Vtil
    for (int t = 0; t < 4; t++) {
      int idx = t * 512 + tid;
      int ci = idx >> 8, hh = (idx >> 5) & 7, w = idx & 31;
      int c = c0 + ci;
      float ar = 0, ai = 0;
      const float* vp = Vtil + ((size_t)c * R * W + w0 + w) * 2;
      #pragma unroll 8
      for (int r = 0; r < R; r++) {
        float vr = vp[(size_t)r * W * 2], vi = vp[(size_t)r * W * 2 + 1];
        float gr = g[ci][hh][r][0], gi = g[ci][hh][r][1];
        ar += gr * vr - gi * vi;
        ai += gr * vi + gi * vr;
      }
      ybuf[ci][hh][w][0] = ar; ybuf[ci][hh][w][1] = ai;
    }
    __syncthreads();
    // z += projW * y
    #pragma unroll
    for (int ci = 0; ci < 8; ci++) {
      int c = c0 + ci;
      float4 y01 = *(const float4*)&ybuf[ci][lh][4 * lw][0];
      float4 y23 = *(const float4*)&ybuf[ci][lh][4 * lw + 2][0];
      float yrv[4] = {y01.x, y01.z, y23.x, y23.z};
      float yiv[4] = {y01.y, y01.w, y23.y, y23.w};
      #pragma unroll
      for (int a = 0; a < 8; a++) {
        float wr = pwr[(ob + a) * C + c], wi = pwi[(ob + a) * C + c];
        #pragma unroll
        for (int j = 0; j < 4; j++) {
          zr[a][j] += wr * yrv[j] - wi * yiv[j];
          zi[a][j] += wr * yiv[j] + wi * yrv[j];
        }
      }
    }
  }
  // spectral conv (Q) + projb
  int hh = h0 + lh;
  #pragma unroll
  for (int a = 0; a < 8; a++) {
    int o = ob + a;
    const float* qp = Qb + ((size_t)(bl * C + o) * H + hh) * 8 * 2;
    #pragma unroll
    for (int m2 = 0; m2 < 8; m2++) {
      float qr2 = qp[2 * m2], qi2 = qp[2 * m2 + 1];
      #pragma unroll
      for (int j = 0; j < 4; j++) {
        int w = w0 + 4 * lw + j;
        int ph = (m2 * w) & 127;
        float cs = t128[2 * ph], sn = t128[2 * ph + 1];
        zr[a][j] += qr2 * cs - qi2 * sn;
        zi[a][j] += qr2 * sn + qi2 * cs;
      }
    }
    if (hh == 0 && w0 == 0 && lw == 0) {
      zr[a][0] += pbr[o]; zi[a][0] += pbi[o];
    }
  }
  // pack 8 contiguous o per pixel, store bf16
  #pragma unroll
  for (int j = 0; j < 4; j++) {
    unsigned tr[4], ti[4];
    #pragma unroll
    for (int q = 0; q < 4; q++) {
      tr[q] = (unsigned)f2bf(zr[2 * q][j]) | ((unsigned)f2bf(zr[2 * q + 1][j]) << 16);
      ti[q] = (unsigned)f2bf(zi[2 * q][j]) | ((unsigned)f2bf(zi[2 * q + 1][j]) << 16);
    }
    size_t zoff = (((size_t)bl * H + hh) * W + (w0 + 4 * lw + j)) * C + ob;
    *(uint4*)(Zr + zoff) = make_uint4(tr[0], tr[1], tr[2], tr[3]);
    *(uint4*)(Zi + zoff) = make_uint4(ti[0], ti[1], ti[2], ti[3]);
  }
}

// ------------------ MFMA implicit-GEMM 3x3 conv (both planes) -> out_pre
// grid BL*H (one output row), 256 thr = 4 waves; wave owns 32 w, block 64 o.
// K = p(2) x dh(3) x kc(2) x dw(3) = 36 steps of 32 channels.
__global__ __launch_bounds__(256) void k_conv(const unsigned short* __restrict__ Zr,
                                              const unsigned short* __restrict__ Zi,
                                              const unsigned short* __restrict__ Wb,
                                              const float* __restrict__ btil,
                                              float* __restrict__ outp) {
  int bl = blockIdx.x >> 6;
  int h = blockIdx.x & 63;
  int tid = threadIdx.x;
  int lane = tid & 63;
  int wv = __builtin_amdgcn_readfirstlane(tid >> 6);
  __shared__ __align__(16) char zs[130 * 128];   // [ws(130)][c(64)] bf16, XOR-swz
  f32x4 acc[4][2];
  #pragma unroll
  for (int mt = 0; mt < 4; mt++)
    for (int nt = 0; nt < 2; nt++) acc[mt][nt] = (f32x4){0, 0, 0, 0};

  for (int p = 0; p < 2; p++) {
    const unsigned short* Z = p ? Zi : Zr;
    for (int dh = 0; dh < 3; dh++) {
      int hr = h + dh - 1;
      __syncthreads();
      // ---- stage row [130][64] bf16 into LDS with XOR swizzle
      if (hr >= 0 && hr < H) {
        const uint4* src = (const uint4*)(Z + ((size_t)(bl * H + hr)) * W * C);
        #pragma unroll
        for (int i = 0; i < 4; i++) {
          int ch = tid * 4 + i;              // 1024 chunks of 16B
          int ws = 1 + (ch >> 3), c2 = (ch & 7) * 16;
          int byte = (ws * 128 + c2) ^ ((ws & 7) << 4);
          *(uint4*)(zs + byte) = src[ch];
        }
      } else {
        #pragma unroll
        for (int i = 0; i < 4; i++) {
          int ch = tid * 4 + i;
          int ws = 1 + (ch >> 3), c2 = (ch & 7) * 16;
          int byte = (ws * 128 + c2) ^ ((ws & 7) << 4);
          *(uint4*)(zs + byte) = make_uint4(0, 0, 0, 0);
        }
      }
      if (tid < 16) {                        // halo rows w=-1 and w=128
        int ws = (tid < 8) ? 0 : 129; int c2 = (tid & 7) * 16;
        int byte = (ws * 128 + c2) ^ ((ws & 7) << 4);
        *(uint4*)(zs + byte) = make_uint4(0, 0, 0, 0);
      }
      __syncthreads();
      // ---- MFMA over kc x dw
      #pragma unroll
      for (int kc = 0; kc < 2; kc++) {
        #pragma unroll
        for (int dw = 0; dw < 3; dw++) {
          int tap = dh * 3 + dw;
          bf16x8 bfr[2];
          #pragma unroll
          for (int nt = 0; nt < 2; nt++) {
            int ws = wv * 32 + nt * 16 + (lane & 15) + dw;   // input w + 1
            int byte = (ws * 128 + (kc * 32 + (lane >> 4) * 8) * 2) ^ ((ws & 7) << 4);
            bfr[nt] = *(const bf16x8*)(zs + byte);
          }
          const unsigned short* wbp =
              Wb + ((size_t)(p * 9 + tap) * C) * C + kc * 32 + (lane >> 4) * 8;
          #pragma unroll
          for (int mt = 0; mt < 4; mt++) {
            bf16x8 af = *(const bf16x8*)(wbp + (size_t)(mt * 16 + (lane & 15)) * C);
            acc[mt][0] = __builtin_amdgcn_mfma_f32_16x16x32_bf16(af, bfr[0], acc[mt][0], 0, 0, 0);
            acc[mt][1] = __builtin_amdgcn_mfma_f32_16x16x32_bf16(af, bfr[1], acc[mt][1], 0, 0, 0);
          }
        }
      }
    }
  }
  // ---- store: D[m][n]: n(w)=lane&15, m(o)=(lane>>4)*4+r
  #pragma unroll
  for (int mt = 0; mt < 4; mt++) {
    #pragma unroll
    for (int nt = 0; nt < 2; nt++) {
      int w = wv * 32 + nt * 16 + (lane & 15);
      #pragma unroll
      for (int r = 0; r < 4; r++) {
        int o = mt * 16 + (lane >> 4) * 4 + r;
        outp[((size_t)(bl * C + o) * H + h) * W + w] = acc[mt][nt][r] + btil[o];
      }
    }
  }
}

// ------------------------------------------------------------- LN statistics
__global__ __launch_bounds__(256) void k_lnstats(const float* __restrict__ outp,
                                                 float* __restrict__ mu,
                                                 float* __restrict__ rstd) {
  int i = blockIdx.x;
  const float4* p = (const float4*)(outp + (size_t)i * HW);
  float s = 0, q = 0;
  for (int t = threadIdx.x; t < HW / 4; t += 256) {
    float4 v = p[t];
    s += (v.x + v.y) + (v.z + v.w);
    q += (v.x * v.x + v.y * v.y) + (v.z * v.z + v.w * v.w);
  }
  #pragma unroll
  for (int o2 = 32; o2; o2 >>= 1) { s += __shfl_down(s, o2); q += __shfl_down(q, o2); }
  __shared__ float rs[4], rq[4];
  if ((threadIdx.x & 63) == 0) { rs[threadIdx.x >> 6] = s; rq[threadIdx.x >> 6] = q; }
  __syncthreads();
  if (threadIdx.x == 0) {
    float S = rs[0] + rs[1] + rs[2] + rs[3];
    float Q = rq[0] + rq[1] + rq[2] + rq[3];
    float m = S * (1.0f / HW);
    float var = Q * (1.0f / HW) - m * m;
    mu[i] = m; rstd[i] = rsqrtf(var + 1e-5f);
  }
}

// -------------------------------- gate matmul + LN apply + residual (inplace)
__global__ __launch_bounds__(256) void k_final(const float* __restrict__ x,
                                               const float* __restrict__ gw,
                                               const float* __restrict__ gb,
                                               const float* __restrict__ mu,
                                               const float* __restrict__ rstd,
                                               const float* __restrict__ lnw,
                                               const float* __restrict__ lnb,
                                               float* __restrict__ outp) {
  int bl = blockIdx.x >> 6, h = blockIdx.x & 63;
  int tid = threadIdx.x;
  __shared__ float xs[C * W];   // 32KB
  for (int i = tid; i < C * W; i += 256) {
    int c = i >> 7, w = i & 127;
    xs[i] = x[((size_t)(bl * C + c) * H + h) * W + w];
  }
  __syncthreads();
  int w = tid & 127;
  int oh = __builtin_amdgcn_readfirstlane(tid >> 7);  // wave-uniform 0/1
  float glin[32];
  #pragma unroll
  for (int i = 0; i < 32; i++) glin[i] = gb[oh * 32 + i];
  for (int cc = 0; cc < C; cc++) {
    float xv = xs[cc * W + w];
    const float* gwp = gw + (size_t)(oh * 32) * C + cc;
    #pragma unroll
    for (int i = 0; i < 32; i++) glin[i] += gwp[(size_t)i * C] * xv;
  }
  float lw = lnw[h * W + w], lb = lnb[h * W + w];
  #pragma unroll
  for (int i = 0; i < 32; i++) {
    int o = oh * 32 + i;
    size_t off = ((size_t)(bl * C + o) * H + h) * W + w;
    float m = mu[bl * C + o], rs = rstd[bl * C + o];
    float op = outp[off];
    float nrm = (op - m) * rs * lw + lb;
    float sg = 1.0f / (1.0f + expf(-glin[i]));
    outp[off] = xs[o * W + w] + sg * nrm;
  }
}

// ============================================================================
extern "C" void kernel_launch(void* const* d_in, const int* in_sizes, int n_in,
                              void* d_out, int out_size, void* d_ws,
                              size_t ws_size, hipStream_t stream) {
  const float* x       = (const float*)d_in[0];
  const float* nu_log  = (const float*)d_in[1];
  const float* th_log  = (const float*)d_in[2];
  const float* mlp_w1  = (const float*)d_in[3];
  const float* mlp_b1  = (const float*)d_in[4];
  const float* mlp_w2  = (const float*)d_in[5];
  const float* mlp_b2  = (const float*)d_in[6];
  const float* fscale  = (const float*)d_in[7];
  const float* U_r     = (const float*)d_in[8];
  const float* U_i     = (const float*)d_in[9];
  const float* V_r     = (const float*)d_in[10];
  const float* V_i     = (const float*)d_in[11];
  const float* pW_r    = (const float*)d_in[12];
  const float* pW_i    = (const float*)d_in[13];
  const float* pb_r    = (const float*)d_in[14];
  const float* pb_i    = (const float*)d_in[15];
  const float* swr1    = (const float*)d_in[16];
  const float* swi1    = (const float*)d_in[17];
  const float* swr2    = (const float*)d_in[18];
  const float* swi2    = (const float*)d_in[19];
  const float* convr_w = (const float*)d_in[20];
  const float* convr_b = (const float*)d_in[21];
  const float* convi_w = (const float*)d_in[22];
  const float* convi_b = (const float*)d_in[23];
  const float* fuse_w  = (const float*)d_in[24];
  const float* fuse_b  = (const float*)d_in[25];
  const float* gate_w  = (const float*)d_in[26];
  const float* gate_b  = (const float*)d_in[27];
  const float* ln_w    = (const float*)d_in[28];
  const float* ln_b    = (const float*)d_in[29];
  float* outp = (float*)d_out;

  char* wsb = (char*)d_ws;
  size_t off = 0;
  auto alloc = [&](size_t nbytes) -> void* {
    void* p = (void*)(wsb + off);
    off += ((nbytes + 255) / 256) * 256;
    return p;
  };
  float* trig64  = (float*)alloc(128 * 4);
  float* trig128 = (float*)alloc(256 * 4);
  float* Uhat = (float*)alloc((size_t)C * H * R * 2 * 4);
  float* Util = (float*)alloc((size_t)C * H * R * 2 * 4);
  float* Vhat = (float*)alloc((size_t)C * W * R * 2 * 4);
  float* Vtil = (float*)alloc((size_t)C * W * R * 2 * 4);
  unsigned short* Wb = (unsigned short*)alloc((size_t)2 * 9 * C * C * 2);
  float* btil = (float*)alloc(C * 4);
  float* ctx  = (float*)alloc(BL * C * 4);
  float* lamr = (float*)alloc(BL * CR * 4);
  float* lami = (float*)alloc(BL * CR * 4);
  float* gam  = (float*)alloc(BL * CR * 4);
  float* ub   = (float*)alloc((size_t)BL * CR * 2 * 4);
  float* hs   = (float*)alloc((size_t)BL * CR * 2 * 4);
  float* Xm   = (float*)alloc((size_t)BL * C * 128 * 2 * 4);
  float* SPm  = (float*)alloc((size_t)BL * C * 128 * 2 * 4);
  float* Qb   = (float*)alloc((size_t)BL * C * H * 8 * 2 * 4);
  unsigned short* Zr = (unsigned short*)alloc((size_t)BL * HW * C * 2);
  unsigned short* Zi = (unsigned short*)alloc((size_t)BL * HW * C * 2);
  float* mu   = (float*)alloc(BL * C * 4);
  float* rstd = (float*)alloc(BL * C * 4);

  k_trig<<<1, 128, 0, stream>>>(trig64, trig128);
  k_utab<<<C, 256, 0, stream>>>(U_r, U_i, trig64, Uhat, Util);
  k_vtab<<<C, 256, 0, stream>>>(V_r, V_i, trig128, Vhat, Vtil);
  k_wb<<<2 * C, 256, 0, stream>>>(fuse_w, convr_w, convi_w, Wb);
  k_btil<<<1, 64, 0, stream>>>(fuse_w, convr_b, convi_b, fuse_b, btil);
  k_ctx<<<BL * C, 256, 0, stream>>>(x, ctx);
  k_mlp<<<BL, 256, 0, stream>>>(ctx, mlp_w1, mlp_b1, mlp_w2, mlp_b2, fscale,
                                nu_log, th_log, lamr, lami, gam);
  k_encode<<<BL * C, 256, 0, stream>>>(x, Vhat, Uhat, trig64, trig128, ub, Xm);
  k_scan<<<16, 256, 0, stream>>>(lamr, lami, gam, ub, hs);
  k_spm<<<dim3(BL, 8), 256, 0, stream>>>(Xm, swr1, swi1, swr2, swi2, SPm);
  k_q<<<BL * C, 256, 0, stream>>>(SPm, trig64, Qb);
  k_decode<<<dim3(BL, 8, 4), 512, 0, stream>>>(hs, Util, Vtil, pW_r, pW_i,
                                               pb_r, pb_i, Qb, trig128, Zr, Zi);
  k_conv<<<BL * H, 256, 0, stream>>>(Zr, Zi, Wb, btil, outp);
  k_lnstats<<<BL * C, 256, 0, stream>>>(outp, mu, rstd);
  k_final<<<BL * H, 256, 0, stream>>>(x, gate_w, gate_b, mu, rstd, ln_w, ln_b,
                                      outp);
}

// Round 5
// 1056.660 us; speedup vs baseline: 2.2928x; 1.8019x over previous
//
#include <hip/hip_runtime.h>
#include <math.h>

// ============================================================================
// ConvLRUBlock on MI355X — round 3 (resubmit #2 after infra timeouts): decode
// via MFMA (k_y + k_proj). y2 pixel-major bf16 [pix][c,ri] pre-swizzled; proj =
// real K=128 GEMM with interleaved complex weights; conv = MFMA implicit GEMM.
// ============================================================================

constexpr int B_ = 2, L_ = 16, C = 64, H = 64, W = 128, R = 32, MH = 32;
constexpr int BL = B_ * L_;     // 32
constexpr int HW = H * W;       // 8192
constexpr int CR = C * R;       // 2048
constexpr float PI2 = 6.28318530717958647692f;

#define DEV __device__ __forceinline__

typedef __attribute__((ext_vector_type(8))) short bf16x8;
typedef __attribute__((ext_vector_type(4))) float f32x4;

static DEV unsigned short f2bf(float f) {
  unsigned u = __float_as_uint(f);
  u = u + 0x7fffu + ((u >> 16) & 1u);
  return (unsigned short)(u >> 16);
}

// ---------------------------------------------------------------- trig tables
__global__ __launch_bounds__(128) void k_trig(float* __restrict__ t64,
                                              float* __restrict__ t128) {
  int i = threadIdx.x;
  if (i < 64) {
    float s, c; sincosf(PI2 * (float)i / 64.0f, &s, &c);
    t64[2 * i] = c; t64[2 * i + 1] = s;
  }
  float s, c; sincosf(PI2 * (float)i / 128.0f, &s, &c);
  t128[2 * i] = c; t128[2 * i + 1] = s;
}

// ------------------------------------------------- U tables: fwd DFT, inv DFT
__global__ __launch_bounds__(256) void k_utab(const float* __restrict__ Ur,
                                              const float* __restrict__ Ui,
                                              const float* __restrict__ t64,
                                              float* __restrict__ Uhat,
                                              float* __restrict__ Util) {
  int c = blockIdx.x;
  __shared__ float tt[128];
  if (threadIdx.x < 128) tt[threadIdx.x] = t64[threadIdx.x];
  __syncthreads();
  for (int t = 0; t < 8; t++) {
    int idx = t * 256 + threadIdx.x;
    int hp = idx >> 5, r = idx & 31;
    float fr = 0, fi = 0, br = 0, bi = 0;
    for (int h = 0; h < H; h++) {
      float ur = Ur[(c * H + h) * R + r], ui = Ui[(c * H + h) * R + r];
      int ph = (h * hp) & 63;
      float cs = tt[2 * ph], sn = tt[2 * ph + 1];
      fr += ur * cs + ui * sn;
      fi += ui * cs - ur * sn;
      br += ur * cs - ui * sn;
      bi += ui * cs + ur * sn;
    }
    int o = ((c * H + hp) * R + r) * 2;
    Uhat[o] = fr; Uhat[o + 1] = fi;
    Util[o] = br * (1.0f / H); Util[o + 1] = bi * (1.0f / H);
  }
}

// Vhat[c][wp][r] fp32 (fwd, for encode);  Vt2r/Vt2i[c][wp][r] bf16 (inv, 1/W)
__global__ __launch_bounds__(256) void k_vtab(const float* __restrict__ Vr,
                                              const float* __restrict__ Vi,
                                              const float* __restrict__ t128,
                                              float* __restrict__ Vhat,
                                              unsigned short* __restrict__ Vt2r,
                                              unsigned short* __restrict__ Vt2i) {
  int c = blockIdx.x;
  __shared__ float tt[256];
  tt[threadIdx.x] = t128[threadIdx.x];
  __syncthreads();
  for (int t = 0; t < 16; t++) {
    int idx = t * 256 + threadIdx.x;
    int wp = idx >> 5, r = idx & 31;
    float fr = 0, fi = 0, br = 0, bi = 0;
    for (int w = 0; w < W; w++) {
      float vr = Vr[(c * W + w) * R + r], vi = Vi[(c * W + w) * R + r];
      int ph = (w * wp) & 127;
      float cs = tt[2 * ph], sn = tt[2 * ph + 1];
      fr += vr * cs + vi * sn;
      fi += vi * cs - vr * sn;
      br += vr * cs - vi * sn;
      bi += vi * cs + vr * sn;
    }
    int of = ((c * W + wp) * R + r) * 2;
    Vhat[of] = fr; Vhat[of + 1] = fi;
    Vt2r[(size_t)(c * W + wp) * R + r] = f2bf(br * (1.0f / W));
    Vt2i[(size_t)(c * W + wp) * R + r] = f2bf(bi * (1.0f / W));
  }
}

// ---------------- fold fuse_w into conv weights, MFMA A-frag order, bf16
__global__ __launch_bounds__(256) void k_wb(const float* __restrict__ fuse_w,
                                            const float* __restrict__ convr_w,
                                            const float* __restrict__ convi_w,
                                            unsigned short* __restrict__ Wb) {
  int po = blockIdx.x; int p = po >> 6, o = po & 63;
  const float* cw = p ? convi_w : convr_w;
  __shared__ float fw[64];
  if (threadIdx.x < 64) fw[threadIdx.x] = fuse_w[o * (2 * C) + p * C + threadIdx.x];
  __syncthreads();
  for (int t = 0; t < 3; t++) {
    int idx = t * 256 + threadIdx.x;      // tap*64 + c
    if (idx < 576) {
      int tap = idx >> 6, c = idx & 63;
      float s = 0;
      for (int k = 0; k < C; k++) s += fw[k] * cw[(k * C + c) * 9 + tap];
      Wb[((size_t)(p * 9 + tap) * C + o) * C + c] = f2bf(s);
    }
  }
}

__global__ __launch_bounds__(64) void k_btil(const float* __restrict__ fuse_w,
                                             const float* __restrict__ rb,
                                             const float* __restrict__ ib,
                                             const float* __restrict__ fb,
                                             float* __restrict__ btil) {
  int o = threadIdx.x;
  float s = fb[o];
  for (int k = 0; k < C; k++)
    s += fuse_w[o * (2 * C) + k] * rb[k] + fuse_w[o * (2 * C) + C + k] * ib[k];
  btil[o] = s;
}

// --------------- P2: interleaved complex proj weights, bf16, pre-swizzled
// P2r[o][2c]=Pr, P2r[o][2c+1]=-Pi ; P2i[o][2c]=Pi, P2i[o][2c+1]=Pr
__global__ __launch_bounds__(128) void k_p2(const float* __restrict__ pwr,
                                            const float* __restrict__ pwi,
                                            unsigned short* __restrict__ P2) {
  int o = blockIdx.x;
  int k = threadIdx.x;           // 0..127
  int c = k >> 1, odd = k & 1;
  float pr = pwr[o * C + c], pi = pwi[o * C + c];
  float vr = odd ? -pi : pr;
  float vi = odd ? pr : pi;
  int boff = (k * 2) ^ ((o & 7) << 4);
  *(unsigned short*)((char*)P2 + o * 256 + boff) = f2bf(vr);
  *(unsigned short*)((char*)P2 + 16384 + o * 256 + boff) = f2bf(vi);
}

// ------------------------------------------------------------- ctx = mean_hw
__global__ __launch_bounds__(256) void k_ctx(const float* __restrict__ x,
                                             float* __restrict__ ctx) {
  int blc = blockIdx.x;
  const float4* px = (const float4*)(x + (size_t)blc * HW);
  float s = 0;
  for (int i = threadIdx.x; i < HW / 4; i += 256) {
    float4 v = px[i];
    s += (v.x + v.y) + (v.z + v.w);
  }
  #pragma unroll
  for (int o2 = 32; o2; o2 >>= 1) s += __shfl_down(s, o2);
  __shared__ float red[4];
  if ((threadIdx.x & 63) == 0) red[threadIdx.x >> 6] = s;
  __syncthreads();
  if (threadIdx.x == 0)
    ctx[blc] = (red[0] + red[1] + red[2] + red[3]) * (1.0f / HW);
}

// --------------------------------------------- MLP forcing -> lam, gamma
__global__ __launch_bounds__(256) void k_mlp(const float* __restrict__ ctx,
                                             const float* __restrict__ w1,
                                             const float* __restrict__ b1,
                                             const float* __restrict__ w2,
                                             const float* __restrict__ b2,
                                             const float* __restrict__ fs_p,
                                             const float* __restrict__ nu_log,
                                             const float* __restrict__ th_log,
                                             float* __restrict__ lamr,
                                             float* __restrict__ lami,
                                             float* __restrict__ gam) {
  int bl = blockIdx.x;
  __shared__ float cs[C];
  __shared__ float hm[MH];
  if (threadIdx.x < C) cs[threadIdx.x] = ctx[bl * C + threadIdx.x];
  __syncthreads();
  if (threadIdx.x < MH) {
    float s = b1[threadIdx.x];
    for (int k = 0; k < C; k++) s += cs[k] * w1[k * MH + threadIdx.x];
    hm[threadIdx.x] = tanhf(s);
  }
  __syncthreads();
  float fs = fs_p[0];
  for (int t = 0; t < 8; t++) {
    int idx = t * 256 + threadIdx.x;       // (c,r) flat over CR
    float d0 = b2[idx], d1 = b2[CR + idx];
    for (int m = 0; m < MH; m++) {
      float hv = hm[m];
      d0 += hv * w2[m * (2 * CR) + idx];
      d1 += hv * w2[m * (2 * CR) + CR + idx];
    }
    float nu = expf(nu_log[idx] + fs * d0);
    float th = expf(th_log[idx] + fs * d1);
    float en = expf(-nu);
    float sn, cn; sincosf(th, &sn, &cn);
    int o = bl * CR + idx;
    lamr[o] = en * cn; lami[o] = en * sn;
    gam[o] = sqrtf(fmaxf(0.0f, 1.0f - en * en));
  }
}

// --------------------------- encode: u[b,l,c,r] and low-mode spectrum Xm
__global__ __launch_bounds__(256) void k_encode(const float* __restrict__ x,
                                                const float* __restrict__ Vhat,
                                                const float* __restrict__ Uhat,
                                                const float* __restrict__ t64,
                                                const float* __restrict__ t128,
                                                float* __restrict__ ub,
                                                float* __restrict__ Xm) {
  int blc = blockIdx.x;
  int c = blc & 63;
  __shared__ float sarr[H * R * 2];   // [h][r][2]  16KB
  __shared__ float fh[16 * W * 2];    // [i1][w][2] 16KB
  int tid = threadIdx.x;
  const float* px = x + (size_t)blc * HW;
  // s[h][r] = sum_w x[h][w] * Vhat[w][r]
  {
    int rp = tid & 15, hb = tid >> 4;
    float ar[4][4];
    #pragma unroll
    for (int q = 0; q < 4; q++)
      for (int j = 0; j < 4; j++) ar[q][j] = 0;
    const float* vp = Vhat + ((size_t)c * W * R + 2 * rp) * 2;
    for (int ww = 0; ww < W; ww++) {
      float4 vv = *(const float4*)(vp + (size_t)ww * R * 2);
      #pragma unroll
      for (int q = 0; q < 4; q++) {
        float xv = px[(hb + 16 * q) * W + ww];
        ar[q][0] += xv * vv.x; ar[q][1] += xv * vv.y;
        ar[q][2] += xv * vv.z; ar[q][3] += xv * vv.w;
      }
    }
    #pragma unroll
    for (int q = 0; q < 4; q++) {
      int h = hb + 16 * q;
      *(float4*)&sarr[(h * R + 2 * rp) * 2] =
          make_float4(ar[q][0], ar[q][1], ar[q][2], ar[q][3]);
    }
  }
  __syncthreads();
  // u[r] = sum_h Uhat[h][r] * s[h][r]
  if (tid < R) {
    int r = tid;
    float ar = 0, ai = 0;
    const float* up = Uhat + ((size_t)c * H * R + r) * 2;
    for (int h2 = 0; h2 < H; h2++) {
      float sr = sarr[(h2 * R + r) * 2], si = sarr[(h2 * R + r) * 2 + 1];
      float ur = up[(size_t)h2 * R * 2], ui2 = up[(size_t)h2 * R * 2 + 1];
      ar += ur * sr - ui2 * si;
      ai += ur * si + ui2 * sr;
    }
    ub[((size_t)blc * R + r) * 2] = ar;
    ub[((size_t)blc * R + r) * 2 + 1] = ai;
  }
  // Fh[i1][w] = sum_h x[h][w] e^{-2pi i m1 h/64}
  {
    int wq = tid & 127, ip = tid >> 7;
    for (int t = 0; t < 8; t++) {
      int i1 = t * 2 + ip;
      int m1 = i1 < 8 ? i1 : 48 + i1;
      float fr = 0, fi = 0;
      for (int h2 = 0; h2 < H; h2++) {
        float xv = px[h2 * W + wq];
        int ph = (m1 * h2) & 63;
        fr += xv * t64[2 * ph];
        fi -= xv * t64[2 * ph + 1];
      }
      fh[(i1 * W + wq) * 2] = fr; fh[(i1 * W + wq) * 2 + 1] = fi;
    }
  }
  __syncthreads();
  // Xm[i1][m2] = sum_w Fh[i1][w] e^{-2pi i m2 w/128}
  if (tid < 128) {
    int i1 = tid >> 3, m2 = tid & 7;
    float ar = 0, ai = 0;
    for (int ww = 0; ww < W; ww++) {
      float fr = fh[(i1 * W + ww) * 2], fi = fh[(i1 * W + ww) * 2 + 1];
      int ph = (m2 * ww) & 127;
      float cs = t128[2 * ph], sn = t128[2 * ph + 1];
      ar += fr * cs + fi * sn;
      ai += fi * cs - fr * sn;
    }
    Xm[((size_t)blc * 128 + tid) * 2] = ar;
    Xm[((size_t)blc * 128 + tid) * 2 + 1] = ai;
  }
}

// ------------------------------------------------- sequential scan over L=16
__global__ __launch_bounds__(256) void k_scan(const float* __restrict__ lamr,
                                              const float* __restrict__ lami,
                                              const float* __restrict__ gam,
                                              const float* __restrict__ ub,
                                              float* __restrict__ hs) {
  int idx = blockIdx.x * 256 + threadIdx.x;   // over B*C*R = 4096
  int b = idx >> 11, cr = idx & 2047;
  float hr = 0, hi = 0;
  for (int l = 0; l < L_; l++) {
    int o = (b * L_ + l) * CR + cr;
    float lr = lamr[o], li = lami[o], g = gam[o];
    float ur = ub[2 * o], ui = ub[2 * o + 1];
    float nr = lr * hr - li * hi + g * ur;
    float ni = lr * hi + li * hr + g * ui;
    hr = nr; hi = ni;
    hs[2 * o] = hr; hs[2 * o + 1] = hi;
  }
}

// ------------------------ spectral conv: mode mix (w1 low rows, w2 high rows)
__global__ __launch_bounds__(256) void k_spm(const float* __restrict__ Xm,
                                             const float* __restrict__ w1r,
                                             const float* __restrict__ w1i,
                                             const float* __restrict__ w2r,
                                             const float* __restrict__ w2i,
                                             float* __restrict__ SPm) {
  int bl = blockIdx.x;
  int o0 = blockIdx.y * 8;
  const float* px = Xm + (size_t)bl * C * 256;
  for (int t = 0; t < 4; t++) {
    int idx = t * 256 + threadIdx.x;      // local o*128 + mode, 1024 items
    int o = o0 + (idx >> 7), mode = idx & 127;
    int i1 = mode >> 3, m2 = mode & 7;
    const float* wr; const float* wi; int ii;
    if (i1 < 8) { wr = w1r; wi = w1i; ii = i1; }
    else        { wr = w2r; wi = w2i; ii = i1 - 8; }
    float ar = 0, ai = 0;
    for (int cc = 0; cc < C; cc++) {
      float xr = px[(cc * 128 + mode) * 2], xi = px[(cc * 128 + mode) * 2 + 1];
      float wrr = wr[((size_t)(o * C + cc) * 8 + ii) * 8 + m2];
      float wii = wi[((size_t)(o * C + cc) * 8 + ii) * 8 + m2];
      ar += xr * wrr - xi * wii;
      ai += xr * wii + xi * wrr;
    }
    size_t oo = (size_t)bl * C * 128 + (size_t)o * 128 + mode;
    SPm[oo * 2] = ar * (1.0f / HW);
    SPm[oo * 2 + 1] = ai * (1.0f / HW);
  }
}

// ---------------- Q[blo][h][m2] = sum_i1 SPm[blo][i1][m2] e^{+2pi i m1 h/64}
__global__ __launch_bounds__(256) void k_q(const float* __restrict__ SPm,
                                           const float* __restrict__ t64,
                                           float* __restrict__ Qb) {
  int blo = blockIdx.x;                 // bl*64 + o
  __shared__ float sp[256];
  int tid = threadIdx.x;
  sp[tid] = SPm[(size_t)blo * 256 + tid];
  __syncthreads();
  for (int t = 0; t < 2; t++) {
    int idx = t * 256 + tid;
    int h = idx >> 3, m2 = idx & 7;
    float ar = 0, ai = 0;
    #pragma unroll
    for (int i1 = 0; i1 < 16; i1++) {
      int m1 = i1 < 8 ? i1 : 48 + i1;
      int ph = (m1 * h) & 63;
      float cs = t64[2 * ph], sn = t64[2 * ph + 1];
      float sr = sp[(i1 * 8 + m2) * 2], si = sp[(i1 * 8 + m2) * 2 + 1];
      ar += sr * cs - si * sn;
      ai += sr * sn + si * cs;
    }
    Qb[((size_t)blo * H * 8 + idx) * 2] = ar;
    Qb[((size_t)blo * H * 8 + idx) * 2 + 1] = ai;
  }
}

// ---------------- k_y: y[bl,c,h,w] = sum_r (hs*Util) * Vtil  via MFMA.
// grid (32 bl, 4 h-tiles of 16, 32 = wtile*16+chunk), 256 thr = 4 waves.
// wave wv handles c = chunk*4+wv: GEMM M=16(h) x N=64(w) x K=32(r).
// Output y2: [pix][c*4B (r,i bf16)] with byte-off XOR (pix&7)<<4 pre-swizzle.
__global__ __launch_bounds__(256) void k_y(
    const float* __restrict__ hs, const float* __restrict__ Util,
    const unsigned short* __restrict__ Vt2r,
    const unsigned short* __restrict__ Vt2i,
    unsigned* __restrict__ y2) {
  int bl = blockIdx.x;
  int h0 = blockIdx.y * 16;
  int zz = blockIdx.z;
  int w0 = (zz >> 4) * 64;
  int chunk = zz & 15;
  int tid = threadIdx.x;
  int lane = tid & 63;
  int wv = __builtin_amdgcn_readfirstlane(tid >> 6);
  __shared__ unsigned ybuf[1024 * 4];   // [pix local 16h*64w][4 c] u32 16KB
  int row = lane & 15;          // A: m(h) / B: n(w) index
  int kg = lane >> 4;           // k-group
  int c = chunk * 4 + wv;
  // A-frags: G = hs * Util  (fp32 -> bf16)
  const float* up = Util + (((size_t)c * H + h0 + row) * R + kg * 8) * 2;
  const float* hp = hs + (((size_t)bl * C + c) * R + kg * 8) * 2;
  bf16x8 aGr, aGi, aGn;
  #pragma unroll
  for (int j = 0; j < 8; j++) {
    float ur = up[2 * j], ui = up[2 * j + 1];
    float hr = hp[2 * j], hi = hp[2 * j + 1];
    float gr = hr * ur - hi * ui, gi = hr * ui + hi * ur;
    aGr[j] = (short)f2bf(gr); aGi[j] = (short)f2bf(gi);
    aGn[j] = (short)f2bf(-gi);
  }
  #pragma unroll
  for (int nt = 0; nt < 4; nt++) {
    int w = w0 + nt * 16 + row;
    const unsigned short* vr = Vt2r + ((size_t)c * W + w) * R + kg * 8;
    const unsigned short* vi = Vt2i + ((size_t)c * W + w) * R + kg * 8;
    bf16x8 bVr = *(const bf16x8*)vr;
    bf16x8 bVi = *(const bf16x8*)vi;
    f32x4 accr = {0, 0, 0, 0}, acci = {0, 0, 0, 0};
    accr = __builtin_amdgcn_mfma_f32_16x16x32_bf16(aGr, bVr, accr, 0, 0, 0);
    accr = __builtin_amdgcn_mfma_f32_16x16x32_bf16(aGn, bVi, accr, 0, 0, 0);
    acci = __builtin_amdgcn_mfma_f32_16x16x32_bf16(aGr, bVi, acci, 0, 0, 0);
    acci = __builtin_amdgcn_mfma_f32_16x16x32_bf16(aGi, bVr, acci, 0, 0, 0);
    // D: col(w)=lane&15, row(h)=kg*4+r
    #pragma unroll
    for (int r = 0; r < 4; r++) {
      int hl = kg * 4 + r;
      unsigned pk = (unsigned)f2bf(accr[r]) | ((unsigned)f2bf(acci[r]) << 16);
      ybuf[(hl * 64 + nt * 16 + row) * 4 + wv] = pk;
    }
  }
  __syncthreads();
  // gather 16B per pixel (4 c's), write global pre-swizzled
  #pragma unroll
  for (int q = 0; q < 4; q++) {
    int p = q * 256 + tid;              // local pix
    int lh = p >> 6, lw = p & 63;
    uint4 v = *(const uint4*)&ybuf[p * 4];
    size_t pixg = ((size_t)bl * H + h0 + lh) * W + (w0 + lw);
    int off = (chunk * 16) ^ ((lw & 7) << 4);
    *(uint4*)((char*)y2 + pixg * 256 + off) = v;
  }
}

// ---------------- k_proj: z[o][w] = P * y (complex via real K=128) + Q + b
// grid (32 bl, 64 h), 256 thr = 4 waves; wave = 64 o x 32 w.
__global__ __launch_bounds__(256) void k_proj(
    const unsigned* __restrict__ y2, const unsigned short* __restrict__ P2,
    const float* __restrict__ Qb, const float* __restrict__ pbr,
    const float* __restrict__ pbi, const float* __restrict__ t128,
    unsigned short* __restrict__ Zr, unsigned short* __restrict__ Zi) {
  int bl = blockIdx.x;
  int h = blockIdx.y;
  int tid = threadIdx.x, lane = tid & 63;
  int wv = __builtin_amdgcn_readfirstlane(tid >> 6);
  __shared__ __align__(16) char ylds[32768];
  __shared__ __align__(16) char plds[32768];
  // stage y-row (32KB) + P2 (32KB), both already swizzled in global
  {
    const uint4* gy = (const uint4*)((const char*)y2 +
                                     ((size_t)bl * H + h) * W * 256);
    const uint4* gp = (const uint4*)P2;
    uint4* ly = (uint4*)ylds; uint4* lp = (uint4*)plds;
    for (int i = tid; i < 2048; i += 256) ly[i] = gy[i];
    for (int i = tid; i < 2048; i += 256) lp[i] = gp[i];
  }
  __syncthreads();
  int col = lane & 15, kg = lane >> 4;
  f32x4 zr[4][2], zi[4][2];
  #pragma unroll
  for (int mt = 0; mt < 4; mt++)
    for (int nt = 0; nt < 2; nt++) { zr[mt][nt] = (f32x4){0,0,0,0}; zi[mt][nt] = (f32x4){0,0,0,0}; }
  #pragma unroll
  for (int ks = 0; ks < 4; ks++) {
    int koff = ks * 64 + kg * 16;
    bf16x8 ar[4], ai[4];
    #pragma unroll
    for (int mt = 0; mt < 4; mt++) {
      int o = mt * 16 + col;
      int ab = o * 256 + (koff ^ ((o & 7) << 4));
      ar[mt] = *(const bf16x8*)(plds + ab);
      ai[mt] = *(const bf16x8*)(plds + 16384 + ab);
    }
    #pragma unroll
    for (int nt = 0; nt < 2; nt++) {
      int pix = wv * 32 + nt * 16 + col;
      bf16x8 b = *(const bf16x8*)(ylds + pix * 256 + (koff ^ ((pix & 7) << 4)));
      #pragma unroll
      for (int mt = 0; mt < 4; mt++) {
        zr[mt][nt] = __builtin_amdgcn_mfma_f32_16x16x32_bf16(ar[mt], b, zr[mt][nt], 0, 0, 0);
        zi[mt][nt] = __builtin_amdgcn_mfma_f32_16x16x32_bf16(ai[mt], b, zi[mt][nt], 0, 0, 0);
      }
    }
  }
  // epilogue: spectral Q + projb, store Z bf16 pixel-major
  #pragma unroll
  for (int nt = 0; nt < 2; nt++) {
    int w = wv * 32 + nt * 16 + col;
    float csv[8], snv[8];
    #pragma unroll
    for (int m2 = 0; m2 < 8; m2++) {
      int ph = (m2 * w) & 127;
      csv[m2] = t128[2 * ph]; snv[m2] = t128[2 * ph + 1];
    }
    #pragma unroll
    for (int mt = 0; mt < 4; mt++) {
      float vrr[4], vii[4];
      #pragma unroll
      for (int r = 0; r < 4; r++) {
        int o = mt * 16 + kg * 4 + r;
        const float* qp = Qb + ((size_t)(bl * C + o) * H + h) * 16;
        float vr = zr[mt][nt][r], vi = zi[mt][nt][r];
        #pragma unroll
        for (int m2 = 0; m2 < 8; m2++) {
          float qr = qp[2 * m2], qi = qp[2 * m2 + 1];
          vr += qr * csv[m2] - qi * snv[m2];
          vi += qr * snv[m2] + qi * csv[m2];
        }
        if (h == 0 && w == 0) { vr += pbr[o]; vi += pbi[o]; }
        vrr[r] = vr; vii[r] = vi;
      }
      size_t zoff = (((size_t)bl * H + h) * W + w) * C + mt * 16 + kg * 4;
      unsigned p0 = f2bf(vrr[0]) | ((unsigned)f2bf(vrr[1]) << 16);
      unsigned p1 = f2bf(vrr[2]) | ((unsigned)f2bf(vrr[3]) << 16);
      *(uint2*)(Zr + zoff) = make_uint2(p0, p1);
      unsigned q0 = f2bf(vii[0]) | ((unsigned)f2bf(vii[1]) << 16);
      unsigned q1 = f2bf(vii[2]) | ((unsigned)f2bf(vii[3]) << 16);
      *(uint2*)(Zi + zoff) = make_uint2(q0, q1);
    }
  }
}

// ------------------ MFMA implicit-GEMM 3x3 conv (both planes) -> out_pre
__global__ __launch_bounds__(256) void k_conv(const unsigned short* __restrict__ Zr,
                                              const unsigned short* __restrict__ Zi,
                                              const unsigned short* __restrict__ Wb,
                                              const float* __restrict__ btil,
                                              float* __restrict__ outp) {
  int bl = blockIdx.x >> 6;
  int h = blockIdx.x & 63;
  int tid = threadIdx.x;
  int lane = tid & 63;
  int wv = __builtin_amdgcn_readfirstlane(tid >> 6);
  __shared__ __align__(16) char zs[130 * 128];   // [ws(130)][c(64)] bf16, XOR-swz
  f32x4 acc[4][2];
  #pragma unroll
  for (int mt = 0; mt < 4; mt++)
    for (int nt = 0; nt < 2; nt++) acc[mt][nt] = (f32x4){0, 0, 0, 0};

  for (int p = 0; p < 2; p++) {
    const unsigned short* Z = p ? Zi : Zr;
    for (int dh = 0; dh < 3; dh++) {
      int hr = h + dh - 1;
      __syncthreads();
      if (hr >= 0 && hr < H) {
        const uint4* src = (const uint4*)(Z + ((size_t)(bl * H + hr)) * W * C);
        #pragma unroll
        for (int i = 0; i < 4; i++) {
          int ch = tid * 4 + i;
          int ws = 1 + (ch >> 3), c2 = (ch & 7) * 16;
          int byte = (ws * 128 + c2) ^ ((ws & 7) << 4);
          *(uint4*)(zs + byte) = src[ch];
        }
      } else {
        #pragma unroll
        for (int i = 0; i < 4; i++) {
          int ch = tid * 4 + i;
          int ws = 1 + (ch >> 3), c2 = (ch & 7) * 16;
          int byte = (ws * 128 + c2) ^ ((ws & 7) << 4);
          *(uint4*)(zs + byte) = make_uint4(0, 0, 0, 0);
        }
      }
      if (tid < 16) {
        int ws = (tid < 8) ? 0 : 129; int c2 = (tid & 7) * 16;
        int byte = (ws * 128 + c2) ^ ((ws & 7) << 4);
        *(uint4*)(zs + byte) = make_uint4(0, 0, 0, 0);
      }
      __syncthreads();
      #pragma unroll
      for (int kc = 0; kc < 2; kc++) {
        #pragma unroll
        for (int dw = 0; dw < 3; dw++) {
          int tap = dh * 3 + dw;
          bf16x8 bfr[2];
          #pragma unroll
          for (int nt = 0; nt < 2; nt++) {
            int ws = wv * 32 + nt * 16 + (lane & 15) + dw;
            int byte = (ws * 128 + (kc * 32 + (lane >> 4) * 8) * 2) ^ ((ws & 7) << 4);
            bfr[nt] = *(const bf16x8*)(zs + byte);
          }
          const unsigned short* wbp =
              Wb + ((size_t)(p * 9 + tap) * C) * C + kc * 32 + (lane >> 4) * 8;
          #pragma unroll
          for (int mt = 0; mt < 4; mt++) {
            bf16x8 af = *(const bf16x8*)(wbp + (size_t)(mt * 16 + (lane & 15)) * C);
            acc[mt][0] = __builtin_amdgcn_mfma_f32_16x16x32_bf16(af, bfr[0], acc[mt][0], 0, 0, 0);
            acc[mt][1] = __builtin_amdgcn_mfma_f32_16x16x32_bf16(af, bfr[1], acc[mt][1], 0, 0, 0);
          }
        }
      }
    }
  }
  #pragma unroll
  for (int mt = 0; mt < 4; mt++) {
    #pragma unroll
    for (int nt = 0; nt < 2; nt++) {
      int w = wv * 32 + nt * 16 + (lane & 15);
      #pragma unroll
      for (int r = 0; r < 4; r++) {
        int o = mt * 16 + (lane >> 4) * 4 + r;
        outp[((size_t)(bl * C + o) * H + h) * W + w] = acc[mt][nt][r] + btil[o];
      }
    }
  }
}

// ------------------------------------------------------------- LN statistics
__global__ __launch_bounds__(256) void k_lnstats(const float* __restrict__ outp,
                                                 float* __restrict__ mu,
                                                 float* __restrict__ rstd) {
  int i = blockIdx.x;
  const float4* p = (const float4*)(outp + (size_t)i * HW);
  float s = 0, q = 0;
  for (int t = threadIdx.x; t < HW / 4; t += 256) {
    float4 v = p[t];
    s += (v.x + v.y) + (v.z + v.w);
    q += (v.x * v.x + v.y * v.y) + (v.z * v.z + v.w * v.w);
  }
  #pragma unroll
  for (int o2 = 32; o2; o2 >>= 1) { s += __shfl_down(s, o2); q += __shfl_down(q, o2); }
  __shared__ float rs[4], rq[4];
  if ((threadIdx.x & 63) == 0) { rs[threadIdx.x >> 6] = s; rq[threadIdx.x >> 6] = q; }
  __syncthreads();
  if (threadIdx.x == 0) {
    float S = rs[0] + rs[1] + rs[2] + rs[3];
    float Q = rq[0] + rq[1] + rq[2] + rq[3];
    float m = S * (1.0f / HW);
    float var = Q * (1.0f / HW) - m * m;
    mu[i] = m; rstd[i] = rsqrtf(var + 1e-5f);
  }
}

// -------------------------------- gate matmul + LN apply + residual (inplace)
__global__ __launch_bounds__(256) void k_final(const float* __restrict__ x,
                                               const float* __restrict__ gw,
                                               const float* __restrict__ gb,
                                               const float* __restrict__ mu,
                                               const float* __restrict__ rstd,
                                               const float* __restrict__ lnw,
                                               const float* __restrict__ lnb,
                                               float* __restrict__ outp) {
  int bl = blockIdx.x >> 6, h = blockIdx.x & 63;
  int tid = threadIdx.x;
  __shared__ float xs[C * W];   // 32KB
  for (int i = tid; i < C * W; i += 256) {
    int c = i >> 7, w = i & 127;
    xs[i] = x[((size_t)(bl * C + c) * H + h) * W + w];
  }
  __syncthreads();
  int w = tid & 127;
  int oh = __builtin_amdgcn_readfirstlane(tid >> 7);  // wave-uniform 0/1
  float glin[32];
  #pragma unroll
  for (int i = 0; i < 32; i++) glin[i] = gb[oh * 32 + i];
  for (int cc = 0; cc < C; cc++) {
    float xv = xs[cc * W + w];
    const float* gwp = gw + (size_t)(oh * 32) * C + cc;
    #pragma unroll
    for (int i = 0; i < 32; i++) glin[i] += gwp[(size_t)i * C] * xv;
  }
  float lw = lnw[h * W + w], lb = lnb[h * W + w];
  #pragma unroll
  for (int i = 0; i < 32; i++) {
    int o = oh * 32 + i;
    size_t off = ((size_t)(bl * C + o) * H + h) * W + w;
    float m = mu[bl * C + o], rs = rstd[bl * C + o];
    float op = outp[off];
    float nrm = (op - m) * rs * lw + lb;
    float sg = 1.0f / (1.0f + expf(-glin[i]));
    outp[off] = xs[o * W + w] + sg * nrm;
  }
}

// ============================================================================
extern "C" void kernel_launch(void* const* d_in, const int* in_sizes, int n_in,
                              void* d_out, int out_size, void* d_ws,
                              size_t ws_size, hipStream_t stream) {
  const float* x       = (const float*)d_in[0];
  const float* nu_log  = (const float*)d_in[1];
  const float* th_log  = (const float*)d_in[2];
  const float* mlp_w1  = (const float*)d_in[3];
  const float* mlp_b1  = (const float*)d_in[4];
  const float* mlp_w2  = (const float*)d_in[5];
  const float* mlp_b2  = (const float*)d_in[6];
  const float* fscale  = (const float*)d_in[7];
  const float* U_r     = (const float*)d_in[8];
  const float* U_i     = (const float*)d_in[9];
  const float* V_r     = (const float*)d_in[10];
  const float* V_i     = (const float*)d_in[11];
  const float* pW_r    = (const float*)d_in[12];
  const float* pW_i    = (const float*)d_in[13];
  const float* pb_r    = (const float*)d_in[14];
  const float* pb_i    = (const float*)d_in[15];
  const float* swr1    = (const float*)d_in[16];
  const float* swi1    = (const float*)d_in[17];
  const float* swr2    = (const float*)d_in[18];
  const float* swi2    = (const float*)d_in[19];
  const float* convr_w = (const float*)d_in[20];
  const float* convr_b = (const float*)d_in[21];
  const float* convi_w = (const float*)d_in[22];
  const float* convi_b = (const float*)d_in[23];
  const float* fuse_w  = (const float*)d_in[24];
  const float* fuse_b  = (const float*)d_in[25];
  const float* gate_w  = (const float*)d_in[26];
  const float* gate_b  = (const float*)d_in[27];
  const float* ln_w    = (const float*)d_in[28];
  const float* ln_b    = (const float*)d_in[29];
  float* outp = (float*)d_out;

  char* wsb = (char*)d_ws;
  size_t off = 0;
  auto alloc = [&](size_t nbytes) -> void* {
    void* p = (void*)(wsb + off);
    off += ((nbytes + 255) / 256) * 256;
    return p;
  };
  float* trig64  = (float*)alloc(128 * 4);
  float* trig128 = (float*)alloc(256 * 4);
  float* Uhat = (float*)alloc((size_t)C * H * R * 2 * 4);
  float* Util = (float*)alloc((size_t)C * H * R * 2 * 4);
  float* Vhat = (float*)alloc((size_t)C * W * R * 2 * 4);
  unsigned short* Vt2r = (unsigned short*)alloc((size_t)C * W * R * 2);
  unsigned short* Vt2i = (unsigned short*)alloc((size_t)C * W * R * 2);
  unsigned short* Wb = (unsigned short*)alloc((size_t)2 * 9 * C * C * 2);
  float* btil = (float*)alloc(C * 4);
  unsigned short* P2 = (unsigned short*)alloc((size_t)2 * C * 128 * 2);
  float* ctx  = (float*)alloc(BL * C * 4);
  float* lamr = (float*)alloc(BL * CR * 4);
  float* lami = (float*)alloc(BL * CR * 4);
  float* gam  = (float*)alloc(BL * CR * 4);
  float* ub   = (float*)alloc((size_t)BL * CR * 2 * 4);
  float* hs   = (float*)alloc((size_t)BL * CR * 2 * 4);
  float* Xm   = (float*)alloc((size_t)BL * C * 128 * 2 * 4);
  float* SPm  = (float*)alloc((size_t)BL * C * 128 * 2 * 4);
  float* Qb   = (float*)alloc((size_t)BL * C * H * 8 * 2 * 4);
  unsigned* y2 = (unsigned*)alloc((size_t)BL * HW * C * 4);
  unsigned short* Zr = (unsigned short*)alloc((size_t)BL * HW * C * 2);
  unsigned short* Zi = (unsigned short*)alloc((size_t)BL * HW * C * 2);
  float* mu   = (float*)alloc(BL * C * 4);
  float* rstd = (float*)alloc(BL * C * 4);

  k_trig<<<1, 128, 0, stream>>>(trig64, trig128);
  k_utab<<<C, 256, 0, stream>>>(U_r, U_i, trig64, Uhat, Util);
  k_vtab<<<C, 256, 0, stream>>>(V_r, V_i, trig128, Vhat, Vt2r, Vt2i);
  k_wb<<<2 * C, 256, 0, stream>>>(fuse_w, convr_w, convi_w, Wb);
  k_btil<<<1, 64, 0, stream>>>(fuse_w, convr_b, convi_b, fuse_b, btil);
  k_p2<<<C, 128, 0, stream>>>(pW_r, pW_i, P2);
  k_ctx<<<BL * C, 256, 0, stream>>>(x, ctx);
  k_mlp<<<BL, 256, 0, stream>>>(ctx, mlp_w1, mlp_b1, mlp_w2, mlp_b2, fscale,
                                nu_log, th_log, lamr, lami, gam);
  k_encode<<<BL * C, 256, 0, stream>>>(x, Vhat, Uhat, trig64, trig128, ub, Xm);
  k_scan<<<16, 256, 0, stream>>>(lamr, lami, gam, ub, hs);
  k_spm<<<dim3(BL, 8), 256, 0, stream>>>(Xm, swr1, swi1, swr2, swi2, SPm);
  k_q<<<BL * C, 256, 0, stream>>>(SPm, trig64, Qb);
  k_y<<<dim3(BL, 4, 32), 256, 0, stream>>>(hs, Util, Vt2r, Vt2i, y2);
  k_proj<<<dim3(BL, H), 256, 0, stream>>>(y2, P2, Qb, pb_r, pb_i, trig128,
                                          Zr, Zi);
  k_conv<<<BL * H, 256, 0, stream>>>(Zr, Zi, Wb, btil, outp);
  k_lnstats<<<BL * C, 256, 0, stream>>>(outp, mu, rstd);
  k_final<<<BL * H, 256, 0, stream>>>(x, gate_w, gate_b, mu, rstd, ln_w, ln_b,
                                      outp);
}

// Round 7
// 881.228 us; speedup vs baseline: 2.7493x; 1.1991x over previous
//
#include <hip/hip_runtime.h>
#include <math.h>

// ============================================================================
// ConvLRUBlock on MI355X — round 6 (resubmit after infra timeout): MFMA encode
// (+ctx fused), MFMA decode (k_y + k_proj), MFMA implicit-GEMM conv. All DFTs
// folded into precomputed per-channel factors; fuse_w folded into conv weights.
// ============================================================================

constexpr int B_ = 2, L_ = 16, C = 64, H = 64, W = 128, R = 32, MH = 32;
constexpr int BL = B_ * L_;     // 32
constexpr int HW = H * W;       // 8192
constexpr int CR = C * R;       // 2048
constexpr float PI2 = 6.28318530717958647692f;

#define DEV __device__ __forceinline__

typedef __attribute__((ext_vector_type(8))) short bf16x8;
typedef __attribute__((ext_vector_type(4))) float f32x4;

static DEV unsigned short f2bf(float f) {
  unsigned u = __float_as_uint(f);
  u = u + 0x7fffu + ((u >> 16) & 1u);
  return (unsigned short)(u >> 16);
}

// -------------------------------------------- trig tables + DFT-coeff A-frags
// Ehat[row(32)][h(64)] bf16: row = p*16+i1, p=0 -> cos, p=1 -> -sin of
// 2*pi*m1*h/64 with m1 = i1<8 ? i1 : 48+i1   (A-operand for Fh GEMM)
__global__ __launch_bounds__(128) void k_trig(float* __restrict__ t64,
                                              float* __restrict__ t128,
                                              unsigned short* __restrict__ Ehat) {
  int i = threadIdx.x;
  if (i < 64) {
    float s, c; sincosf(PI2 * (float)i / 64.0f, &s, &c);
    t64[2 * i] = c; t64[2 * i + 1] = s;
  }
  float s, c; sincosf(PI2 * (float)i / 128.0f, &s, &c);
  t128[2 * i] = c; t128[2 * i + 1] = s;
  for (int j = 0; j < 16; j++) {
    int idx = j * 128 + i;              // 0..2047
    int row = idx >> 6, hh = idx & 63;
    int i1 = row & 15, p = row >> 4;
    int m1 = i1 < 8 ? i1 : 48 + i1;
    float ang = PI2 * (float)((m1 * hh) & 63) / 64.0f;
    float s2, c2; sincosf(ang, &s2, &c2);
    Ehat[row * 64 + hh] = f2bf(p ? -s2 : c2);
  }
}

// ------------------------------------------------- U tables: fwd DFT, inv DFT
__global__ __launch_bounds__(256) void k_utab(const float* __restrict__ Ur,
                                              const float* __restrict__ Ui,
                                              const float* __restrict__ t64,
                                              float* __restrict__ Uhat,
                                              float* __restrict__ Util) {
  int c = blockIdx.x;
  __shared__ float tt[128];
  if (threadIdx.x < 128) tt[threadIdx.x] = t64[threadIdx.x];
  __syncthreads();
  for (int t = 0; t < 8; t++) {
    int idx = t * 256 + threadIdx.x;
    int hp = idx >> 5, r = idx & 31;
    float fr = 0, fi = 0, br = 0, bi = 0;
    for (int h = 0; h < H; h++) {
      float ur = Ur[(c * H + h) * R + r], ui = Ui[(c * H + h) * R + r];
      int ph = (h * hp) & 63;
      float cs = tt[2 * ph], sn = tt[2 * ph + 1];
      fr += ur * cs + ui * sn;
      fi += ui * cs - ur * sn;
      br += ur * cs - ui * sn;
      bi += ui * cs + ur * sn;
    }
    int o = ((c * H + hp) * R + r) * 2;
    Uhat[o] = fr; Uhat[o + 1] = fi;
    Util[o] = br * (1.0f / H); Util[o + 1] = bi * (1.0f / H);
  }
}

// Vhb[c][2r+comp][w] bf16 (fwd DFT, B-operand for encode GEMM1);
// Vt2r/Vt2i[c][wp][r] bf16 (inv, 1/W — for k_y)
__global__ __launch_bounds__(256) void k_vtab(const float* __restrict__ Vr,
                                              const float* __restrict__ Vi,
                                              const float* __restrict__ t128,
                                              unsigned short* __restrict__ Vhb,
                                              unsigned short* __restrict__ Vt2r,
                                              unsigned short* __restrict__ Vt2i) {
  int c = blockIdx.x;
  __shared__ float tt[256];
  tt[threadIdx.x] = t128[threadIdx.x];
  __syncthreads();
  for (int t = 0; t < 16; t++) {
    int idx = t * 256 + threadIdx.x;
    int wp = idx >> 5, r = idx & 31;
    float fr = 0, fi = 0, br = 0, bi = 0;
    for (int w = 0; w < W; w++) {
      float vr = Vr[(c * W + w) * R + r], vi = Vi[(c * W + w) * R + r];
      int ph = (w * wp) & 127;
      float cs = tt[2 * ph], sn = tt[2 * ph + 1];
      fr += vr * cs + vi * sn;
      fi += vi * cs - vr * sn;
      br += vr * cs - vi * sn;
      bi += vi * cs + vr * sn;
    }
    Vhb[((size_t)c * 64 + 2 * r) * 128 + wp] = f2bf(fr);
    Vhb[((size_t)c * 64 + 2 * r + 1) * 128 + wp] = f2bf(fi);
    Vt2r[(size_t)(c * W + wp) * R + r] = f2bf(br * (1.0f / W));
    Vt2i[(size_t)(c * W + wp) * R + r] = f2bf(bi * (1.0f / W));
  }
}

// ---------------- fold fuse_w into conv weights, MFMA A-frag order, bf16
__global__ __launch_bounds__(256) void k_wb(const float* __restrict__ fuse_w,
                                            const float* __restrict__ convr_w,
                                            const float* __restrict__ convi_w,
                                            unsigned short* __restrict__ Wb) {
  int po = blockIdx.x; int p = po >> 6, o = po & 63;
  const float* cw = p ? convi_w : convr_w;
  __shared__ float fw[64];
  if (threadIdx.x < 64) fw[threadIdx.x] = fuse_w[o * (2 * C) + p * C + threadIdx.x];
  __syncthreads();
  for (int t = 0; t < 3; t++) {
    int idx = t * 256 + threadIdx.x;      // tap*64 + c
    if (idx < 576) {
      int tap = idx >> 6, c = idx & 63;
      float s = 0;
      for (int k = 0; k < C; k++) s += fw[k] * cw[(k * C + c) * 9 + tap];
      Wb[((size_t)(p * 9 + tap) * C + o) * C + c] = f2bf(s);
    }
  }
}

__global__ __launch_bounds__(64) void k_btil(const float* __restrict__ fuse_w,
                                             const float* __restrict__ rb,
                                             const float* __restrict__ ib,
                                             const float* __restrict__ fb,
                                             float* __restrict__ btil) {
  int o = threadIdx.x;
  float s = fb[o];
  for (int k = 0; k < C; k++)
    s += fuse_w[o * (2 * C) + k] * rb[k] + fuse_w[o * (2 * C) + C + k] * ib[k];
  btil[o] = s;
}

// --------------- P2: interleaved complex proj weights, bf16, pre-swizzled
__global__ __launch_bounds__(128) void k_p2(const float* __restrict__ pwr,
                                            const float* __restrict__ pwi,
                                            unsigned short* __restrict__ P2) {
  int o = blockIdx.x;
  int k = threadIdx.x;           // 0..127
  int c = k >> 1, odd = k & 1;
  float pr = pwr[o * C + c], pi = pwi[o * C + c];
  float vr = odd ? -pi : pr;
  float vi = odd ? pr : pi;
  int boff = (k * 2) ^ ((o & 7) << 4);
  *(unsigned short*)((char*)P2 + o * 256 + boff) = f2bf(vr);
  *(unsigned short*)((char*)P2 + 16384 + o * 256 + boff) = f2bf(vi);
}

// --------------------------------------------- MLP forcing -> lam, gamma
__global__ __launch_bounds__(256) void k_mlp(const float* __restrict__ ctx,
                                             const float* __restrict__ w1,
                                             const float* __restrict__ b1,
                                             const float* __restrict__ w2,
                                             const float* __restrict__ b2,
                                             const float* __restrict__ fs_p,
                                             const float* __restrict__ nu_log,
                                             const float* __restrict__ th_log,
                                             float* __restrict__ lamr,
                                             float* __restrict__ lami,
                                             float* __restrict__ gam) {
  int bl = blockIdx.x;
  __shared__ float cs[C];
  __shared__ float hm[MH];
  if (threadIdx.x < C) cs[threadIdx.x] = ctx[bl * C + threadIdx.x];
  __syncthreads();
  if (threadIdx.x < MH) {
    float s = b1[threadIdx.x];
    for (int k = 0; k < C; k++) s += cs[k] * w1[k * MH + threadIdx.x];
    hm[threadIdx.x] = tanhf(s);
  }
  __syncthreads();
  float fs = fs_p[0];
  for (int t = 0; t < 8; t++) {
    int idx = t * 256 + threadIdx.x;       // (c,r) flat over CR
    float d0 = b2[idx], d1 = b2[CR + idx];
    for (int m = 0; m < MH; m++) {
      float hv = hm[m];
      d0 += hv * w2[m * (2 * CR) + idx];
      d1 += hv * w2[m * (2 * CR) + CR + idx];
    }
    float nu = expf(nu_log[idx] + fs * d0);
    float th = expf(th_log[idx] + fs * d1);
    float en = expf(-nu);
    float sn, cn; sincosf(th, &sn, &cn);
    int o = bl * CR + idx;
    lamr[o] = en * cn; lami[o] = en * sn;
    gam[o] = sqrtf(fmaxf(0.0f, 1.0f - en * en));
  }
}

// --------------------------- encode (MFMA): u[b,l,c,r], Xm low modes, ctx
// grid BL*C, 256 thr = 4 waves. LDS: xb[h][w] bf16 16KB (-> s f32 16KB),
// xbt[w][h] bf16 16KB (-> Fh f32 16KB). Both XOR-swizzled.
__global__ __launch_bounds__(256) void k_encode(
    const float* __restrict__ x, const unsigned short* __restrict__ Vhb,
    const float* __restrict__ Uhat, const unsigned short* __restrict__ Ehat,
    const float* __restrict__ t128, float* __restrict__ ub,
    float* __restrict__ Xm, float* __restrict__ ctx) {
  int blc = blockIdx.x;
  int c = blc & 63;
  __shared__ __align__(16) char ldsA[16384];   // xb, then s
  __shared__ __align__(16) char ldsB[16384];   // xbt, then Fh
  __shared__ float red[4];
  int tid = threadIdx.x;
  int lane = tid & 63;
  int wv = __builtin_amdgcn_readfirstlane(tid >> 6);
  int col = lane & 15, kg = lane >> 4;

  // ---- stage x -> bf16 xb[h][w] + xbt[w][h]; accumulate ctx sum
  const float4* px4 = (const float4*)(x + (size_t)blc * HW);
  float csum = 0;
  #pragma unroll
  for (int j = 0; j < 8; j++) {
    int e4 = j * 256 + tid;             // float4 index, 2048 total
    float4 v = px4[e4];
    csum += (v.x + v.y) + (v.z + v.w);
    int elem = e4 * 4;
    int h = elem >> 7, w = elem & 127;
    unsigned p0 = (unsigned)f2bf(v.x) | ((unsigned)f2bf(v.y) << 16);
    unsigned p1 = (unsigned)f2bf(v.z) | ((unsigned)f2bf(v.w) << 16);
    int ba = (h * 256 + w * 2) ^ ((h & 7) << 4);
    *(uint2*)(ldsA + ba) = make_uint2(p0, p1);
    unsigned short t0 = f2bf(v.x), t1 = f2bf(v.y), t2 = f2bf(v.z), t3 = f2bf(v.w);
    *(unsigned short*)(ldsB + (((w + 0) * 128 + h * 2) ^ (((w + 0) & 7) << 4))) = t0;
    *(unsigned short*)(ldsB + (((w + 1) * 128 + h * 2) ^ (((w + 1) & 7) << 4))) = t1;
    *(unsigned short*)(ldsB + (((w + 2) * 128 + h * 2) ^ (((w + 2) & 7) << 4))) = t2;
    *(unsigned short*)(ldsB + (((w + 3) * 128 + h * 2) ^ (((w + 3) & 7) << 4))) = t3;
  }
  #pragma unroll
  for (int m = 32; m; m >>= 1) csum += __shfl_xor(csum, m);
  if (lane == 0) red[wv] = csum;
  __syncthreads();
  if (tid == 0)
    ctx[blc] = (red[0] + red[1] + red[2] + red[3]) * (1.0f / HW);

  // ---- GEMM1: s[h][2r+comp] = x @ Vhat   (M=16h/wave, N=64, K=128)
  f32x4 acc1[4];
  #pragma unroll
  for (int nt = 0; nt < 4; nt++) acc1[nt] = (f32x4){0, 0, 0, 0};
  int hA = wv * 16 + col;
  #pragma unroll
  for (int ks = 0; ks < 4; ks++) {
    int k0 = ks * 32 + kg * 8;
    bf16x8 a = *(const bf16x8*)(ldsA + ((hA * 256 + k0 * 2) ^ ((hA & 7) << 4)));
    #pragma unroll
    for (int nt = 0; nt < 4; nt++) {
      int n = nt * 16 + col;
      bf16x8 b = *(const bf16x8*)(Vhb + ((size_t)c * 64 + n) * 128 + k0);
      acc1[nt] = __builtin_amdgcn_mfma_f32_16x16x32_bf16(a, b, acc1[nt], 0, 0, 0);
    }
  }
  // ---- GEMM2: Fh[p*16+i1][w] = Ehat @ x^T  (M=32, N=32w/wave, K=64)
  f32x4 acc2[2][2];
  #pragma unroll
  for (int mt = 0; mt < 2; mt++)
    for (int nt = 0; nt < 2; nt++) acc2[mt][nt] = (f32x4){0, 0, 0, 0};
  #pragma unroll
  for (int ks = 0; ks < 2; ks++) {
    int k0 = ks * 32 + kg * 8;
    bf16x8 a2[2];
    #pragma unroll
    for (int mt = 0; mt < 2; mt++)
      a2[mt] = *(const bf16x8*)(Ehat + (mt * 16 + col) * 64 + k0);
    #pragma unroll
    for (int nt = 0; nt < 2; nt++) {
      int w = wv * 32 + nt * 16 + col;
      bf16x8 b2 = *(const bf16x8*)(ldsB + ((w * 128 + k0 * 2) ^ ((w & 7) << 4)));
      #pragma unroll
      for (int mt = 0; mt < 2; mt++)
        acc2[mt][nt] = __builtin_amdgcn_mfma_f32_16x16x32_bf16(a2[mt], b2, acc2[mt][nt], 0, 0, 0);
    }
  }
  __syncthreads();   // all LDS reads of xb/xbt complete
  // write s (f32 [64][64], swz) into ldsA; Fh (f32 [32][128], swz) into ldsB
  #pragma unroll
  for (int nt = 0; nt < 4; nt++) {
    int r2 = nt * 16 + col;
    #pragma unroll
    for (int j = 0; j < 4; j++) {
      int h = wv * 16 + kg * 4 + j;
      *(float*)(ldsA + ((h * 256 + r2 * 4) ^ ((h & 7) << 4))) = acc1[nt][j];
    }
  }
  #pragma unroll
  for (int mt = 0; mt < 2; mt++)
    for (int nt = 0; nt < 2; nt++)
      #pragma unroll
      for (int j = 0; j < 4; j++) {
        int mrow = mt * 16 + kg * 4 + j;
        int w = wv * 32 + nt * 16 + col;
        *(float*)(ldsB + ((mrow * 512 + w * 4) ^ ((mrow & 7) << 4))) = acc2[mt][nt][j];
      }
  __syncthreads();

  // ---- u[r] = sum_h Uhat[h][r] (cplx) * s[h][r] (cplx)
  {
    int r = tid >> 3, hg = tid & 7;
    float ar = 0, ai = 0;
    #pragma unroll
    for (int j = 0; j < 8; j++) {
      int h = hg + 8 * j;
      float2 sv = *(const float2*)(ldsA + ((h * 256 + r * 8) ^ ((h & 7) << 4)));
      const float* up = Uhat + (((size_t)c * H + h) * R + r) * 2;
      float ur = up[0], ui = up[1];
      ar += ur * sv.x - ui * sv.y;
      ai += ur * sv.y + ui * sv.x;
    }
    ar += __shfl_xor(ar, 1); ai += __shfl_xor(ai, 1);
    ar += __shfl_xor(ar, 2); ai += __shfl_xor(ai, 2);
    ar += __shfl_xor(ar, 4); ai += __shfl_xor(ai, 4);
    if (hg == 0) {
      ub[((size_t)blc * R + r) * 2] = ar;
      ub[((size_t)blc * R + r) * 2 + 1] = ai;
    }
  }
  // ---- Xm[i1][m2] = sum_w Fh[i1][w] * e^{-2pi i m2 w/128}
  {
    int i1 = tid >> 4, m2 = (tid >> 1) & 7, half = tid & 1;
    float ar = 0, ai = 0;
    for (int jw = 0; jw < 64; jw++) {
      int w = half * 64 + jw;
      float fr = *(const float*)(ldsB + ((i1 * 512 + w * 4) ^ ((i1 & 7) << 4)));
      float fi = *(const float*)(ldsB + (((16 + i1) * 512 + w * 4) ^ ((i1 & 7) << 4)));
      int ph = (m2 * w) & 127;
      float cs = t128[2 * ph], sn = t128[2 * ph + 1];
      ar += fr * cs + fi * sn;
      ai += fi * cs - fr * sn;
    }
    ar += __shfl_xor(ar, 1); ai += __shfl_xor(ai, 1);
    if (half == 0) {
      Xm[((size_t)blc * 128 + i1 * 8 + m2) * 2] = ar;
      Xm[((size_t)blc * 128 + i1 * 8 + m2) * 2 + 1] = ai;
    }
  }
}

// ------------------------------------------------- sequential scan over L=16
__global__ __launch_bounds__(256) void k_scan(const float* __restrict__ lamr,
                                              const float* __restrict__ lami,
                                              const float* __restrict__ gam,
                                              const float* __restrict__ ub,
                                              float* __restrict__ hs) {
  int idx = blockIdx.x * 256 + threadIdx.x;   // over B*C*R = 4096
  int b = idx >> 11, cr = idx & 2047;
  float hr = 0, hi = 0;
  for (int l = 0; l < L_; l++) {
    int o = (b * L_ + l) * CR + cr;
    float lr = lamr[o], li = lami[o], g = gam[o];
    float ur = ub[2 * o], ui = ub[2 * o + 1];
    float nr = lr * hr - li * hi + g * ur;
    float ni = lr * hi + li * hr + g * ui;
    hr = nr; hi = ni;
    hs[2 * o] = hr; hs[2 * o + 1] = hi;
  }
}

// ------------------------ spectral conv: mode mix (w1 low rows, w2 high rows)
__global__ __launch_bounds__(256) void k_spm(const float* __restrict__ Xm,
                                             const float* __restrict__ w1r,
                                             const float* __restrict__ w1i,
                                             const float* __restrict__ w2r,
                                             const float* __restrict__ w2i,
                                             float* __restrict__ SPm) {
  int bl = blockIdx.x;
  int o0 = blockIdx.y * 8;
  const float* px = Xm + (size_t)bl * C * 256;
  for (int t = 0; t < 4; t++) {
    int idx = t * 256 + threadIdx.x;      // local o*128 + mode, 1024 items
    int o = o0 + (idx >> 7), mode = idx & 127;
    int i1 = mode >> 3, m2 = mode & 7;
    const float* wr; const float* wi; int ii;
    if (i1 < 8) { wr = w1r; wi = w1i; ii = i1; }
    else        { wr = w2r; wi = w2i; ii = i1 - 8; }
    float ar = 0, ai = 0;
    for (int cc = 0; cc < C; cc++) {
      float xr = px[(cc * 128 + mode) * 2], xi = px[(cc * 128 + mode) * 2 + 1];
      float wrr = wr[((size_t)(o * C + cc) * 8 + ii) * 8 + m2];
      float wii = wi[((size_t)(o * C + cc) * 8 + ii) * 8 + m2];
      ar += xr * wrr - xi * wii;
      ai += xr * wii + xi * wrr;
    }
    size_t oo = (size_t)bl * C * 128 + (size_t)o * 128 + mode;
    SPm[oo * 2] = ar * (1.0f / HW);
    SPm[oo * 2 + 1] = ai * (1.0f / HW);
  }
}

// ---------------- Q[blo][h][m2] = sum_i1 SPm[blo][i1][m2] e^{+2pi i m1 h/64}
__global__ __launch_bounds__(256) void k_q(const float* __restrict__ SPm,
                                           const float* __restrict__ t64,
                                           float* __restrict__ Qb) {
  int blo = blockIdx.x;                 // bl*64 + o
  __shared__ float sp[256];
  int tid = threadIdx.x;
  sp[tid] = SPm[(size_t)blo * 256 + tid];
  __syncthreads();
  for (int t = 0; t < 2; t++) {
    int idx = t * 256 + tid;
    int h = idx >> 3, m2 = idx & 7;
    float ar = 0, ai = 0;
    #pragma unroll
    for (int i1 = 0; i1 < 16; i1++) {
      int m1 = i1 < 8 ? i1 : 48 + i1;
      int ph = (m1 * h) & 63;
      float cs = t64[2 * ph], sn = t64[2 * ph + 1];
      float sr = sp[(i1 * 8 + m2) * 2], si = sp[(i1 * 8 + m2) * 2 + 1];
      ar += sr * cs - si * sn;
      ai += sr * sn + si * cs;
    }
    Qb[((size_t)blo * H * 8 + idx) * 2] = ar;
    Qb[((size_t)blo * H * 8 + idx) * 2 + 1] = ai;
  }
}

// ---------------- k_y: y[bl,c,h,w] = sum_r (hs*Util) * Vtil  via MFMA.
__global__ __launch_bounds__(256) void k_y(
    const float* __restrict__ hs, const float* __restrict__ Util,
    const unsigned short* __restrict__ Vt2r,
    const unsigned short* __restrict__ Vt2i,
    unsigned* __restrict__ y2) {
  int bl = blockIdx.x;
  int h0 = blockIdx.y * 16;
  int zz = blockIdx.z;
  int w0 = (zz >> 4) * 64;
  int chunk = zz & 15;
  int tid = threadIdx.x;
  int lane = tid & 63;
  int wv = __builtin_amdgcn_readfirstlane(tid >> 6);
  __shared__ unsigned ybuf[1024 * 4];   // [pix local 16h*64w][4 c] u32 16KB
  int row = lane & 15;          // A: m(h) / B: n(w) index
  int kg = lane >> 4;           // k-group
  int c = chunk * 4 + wv;
  const float* up = Util + (((size_t)c * H + h0 + row) * R + kg * 8) * 2;
  const float* hp = hs + (((size_t)bl * C + c) * R + kg * 8) * 2;
  bf16x8 aGr, aGi, aGn;
  #pragma unroll
  for (int j = 0; j < 8; j++) {
    float ur = up[2 * j], ui = up[2 * j + 1];
    float hr = hp[2 * j], hi = hp[2 * j + 1];
    float gr = hr * ur - hi * ui, gi = hr * ui + hi * ur;
    aGr[j] = (short)f2bf(gr); aGi[j] = (short)f2bf(gi);
    aGn[j] = (short)f2bf(-gi);
  }
  #pragma unroll
  for (int nt = 0; nt < 4; nt++) {
    int w = w0 + nt * 16 + row;
    const unsigned short* vr = Vt2r + ((size_t)c * W + w) * R + kg * 8;
    const unsigned short* vi = Vt2i + ((size_t)c * W + w) * R + kg * 8;
    bf16x8 bVr = *(const bf16x8*)vr;
    bf16x8 bVi = *(const bf16x8*)vi;
    f32x4 accr = {0, 0, 0, 0}, acci = {0, 0, 0, 0};
    accr = __builtin_amdgcn_mfma_f32_16x16x32_bf16(aGr, bVr, accr, 0, 0, 0);
    accr = __builtin_amdgcn_mfma_f32_16x16x32_bf16(aGn, bVi, accr, 0, 0, 0);
    acci = __builtin_amdgcn_mfma_f32_16x16x32_bf16(aGr, bVi, acci, 0, 0, 0);
    acci = __builtin_amdgcn_mfma_f32_16x16x32_bf16(aGi, bVr, acci, 0, 0, 0);
    #pragma unroll
    for (int r = 0; r < 4; r++) {
      int hl = kg * 4 + r;
      unsigned pk = (unsigned)f2bf(accr[r]) | ((unsigned)f2bf(acci[r]) << 16);
      ybuf[(hl * 64 + nt * 16 + row) * 4 + wv] = pk;
    }
  }
  __syncthreads();
  #pragma unroll
  for (int q = 0; q < 4; q++) {
    int p = q * 256 + tid;              // local pix
    int lh = p >> 6, lw = p & 63;
    uint4 v = *(const uint4*)&ybuf[p * 4];
    size_t pixg = ((size_t)bl * H + h0 + lh) * W + (w0 + lw);
    int off = (chunk * 16) ^ ((lw & 7) << 4);
    *(uint4*)((char*)y2 + pixg * 256 + off) = v;
  }
}

// ---------------- k_proj: z[o][w] = P * y (complex via real K=128) + Q + b
__global__ __launch_bounds__(256) void k_proj(
    const unsigned* __restrict__ y2, const unsigned short* __restrict__ P2,
    const float* __restrict__ Qb, const float* __restrict__ pbr,
    const float* __restrict__ pbi, const float* __restrict__ t128,
    unsigned short* __restrict__ Zr, unsigned short* __restrict__ Zi) {
  int bl = blockIdx.x;
  int h = blockIdx.y;
  int tid = threadIdx.x, lane = tid & 63;
  int wv = __builtin_amdgcn_readfirstlane(tid >> 6);
  __shared__ __align__(16) char ylds[32768];
  __shared__ __align__(16) char plds[32768];
  {
    const uint4* gy = (const uint4*)((const char*)y2 +
                                     ((size_t)bl * H + h) * W * 256);
    const uint4* gp = (const uint4*)P2;
    uint4* ly = (uint4*)ylds; uint4* lp = (uint4*)plds;
    for (int i = tid; i < 2048; i += 256) ly[i] = gy[i];
    for (int i = tid; i < 2048; i += 256) lp[i] = gp[i];
  }
  __syncthreads();
  int col = lane & 15, kg = lane >> 4;
  f32x4 zr[4][2], zi[4][2];
  #pragma unroll
  for (int mt = 0; mt < 4; mt++)
    for (int nt = 0; nt < 2; nt++) { zr[mt][nt] = (f32x4){0,0,0,0}; zi[mt][nt] = (f32x4){0,0,0,0}; }
  #pragma unroll
  for (int ks = 0; ks < 4; ks++) {
    int koff = ks * 64 + kg * 16;
    bf16x8 ar[4], ai[4];
    #pragma unroll
    for (int mt = 0; mt < 4; mt++) {
      int o = mt * 16 + col;
      int ab = o * 256 + (koff ^ ((o & 7) << 4));
      ar[mt] = *(const bf16x8*)(plds + ab);
      ai[mt] = *(const bf16x8*)(plds + 16384 + ab);
    }
    #pragma unroll
    for (int nt = 0; nt < 2; nt++) {
      int pix = wv * 32 + nt * 16 + col;
      bf16x8 b = *(const bf16x8*)(ylds + pix * 256 + (koff ^ ((pix & 7) << 4)));
      #pragma unroll
      for (int mt = 0; mt < 4; mt++) {
        zr[mt][nt] = __builtin_amdgcn_mfma_f32_16x16x32_bf16(ar[mt], b, zr[mt][nt], 0, 0, 0);
        zi[mt][nt] = __builtin_amdgcn_mfma_f32_16x16x32_bf16(ai[mt], b, zi[mt][nt], 0, 0, 0);
      }
    }
  }
  #pragma unroll
  for (int nt = 0; nt < 2; nt++) {
    int w = wv * 32 + nt * 16 + col;
    float csv[8], snv[8];
    #pragma unroll
    for (int m2 = 0; m2 < 8; m2++) {
      int ph = (m2 * w) & 127;
      csv[m2] = t128[2 * ph]; snv[m2] = t128[2 * ph + 1];
    }
    #pragma unroll
    for (int mt = 0; mt < 4; mt++) {
      float vrr[4], vii[4];
      #pragma unroll
      for (int r = 0; r < 4; r++) {
        int o = mt * 16 + kg * 4 + r;
        const float* qp = Qb + ((size_t)(bl * C + o) * H + h) * 16;
        float vr = zr[mt][nt][r], vi = zi[mt][nt][r];
        #pragma unroll
        for (int m2 = 0; m2 < 8; m2++) {
          float qr = qp[2 * m2], qi = qp[2 * m2 + 1];
          vr += qr * csv[m2] - qi * snv[m2];
          vi += qr * snv[m2] + qi * csv[m2];
        }
        if (h == 0 && w == 0) { vr += pbr[o]; vi += pbi[o]; }
        vrr[r] = vr; vii[r] = vi;
      }
      size_t zoff = (((size_t)bl * H + h) * W + w) * C + mt * 16 + kg * 4;
      unsigned p0 = f2bf(vrr[0]) | ((unsigned)f2bf(vrr[1]) << 16);
      unsigned p1 = f2bf(vrr[2]) | ((unsigned)f2bf(vrr[3]) << 16);
      *(uint2*)(Zr + zoff) = make_uint2(p0, p1);
      unsigned q0 = f2bf(vii[0]) | ((unsigned)f2bf(vii[1]) << 16);
      unsigned q1 = f2bf(vii[2]) | ((unsigned)f2bf(vii[3]) << 16);
      *(uint2*)(Zi + zoff) = make_uint2(q0, q1);
    }
  }
}

// ------------------ MFMA implicit-GEMM 3x3 conv (both planes) -> out_pre
__global__ __launch_bounds__(256) void k_conv(const unsigned short* __restrict__ Zr,
                                              const unsigned short* __restrict__ Zi,
                                              const unsigned short* __restrict__ Wb,
                                              const float* __restrict__ btil,
                                              float* __restrict__ outp) {
  int bl = blockIdx.x >> 6;
  int h = blockIdx.x & 63;
  int tid = threadIdx.x;
  int lane = tid & 63;
  int wv = __builtin_amdgcn_readfirstlane(tid >> 6);
  __shared__ __align__(16) char zs[130 * 128];   // [ws(130)][c(64)] bf16, XOR-swz
  f32x4 acc[4][2];
  #pragma unroll
  for (int mt = 0; mt < 4; mt++)
    for (int nt = 0; nt < 2; nt++) acc[mt][nt] = (f32x4){0, 0, 0, 0};

  for (int p = 0; p < 2; p++) {
    const unsigned short* Z = p ? Zi : Zr;
    for (int dh = 0; dh < 3; dh++) {
      int hr = h + dh - 1;
      __syncthreads();
      if (hr >= 0 && hr < H) {
        const uint4* src = (const uint4*)(Z + ((size_t)(bl * H + hr)) * W * C);
        #pragma unroll
        for (int i = 0; i < 4; i++) {
          int ch = tid * 4 + i;
          int ws = 1 + (ch >> 3), c2 = (ch & 7) * 16;
          int byte = (ws * 128 + c2) ^ ((ws & 7) << 4);
          *(uint4*)(zs + byte) = src[ch];
        }
      } else {
        #pragma unroll
        for (int i = 0; i < 4; i++) {
          int ch = tid * 4 + i;
          int ws = 1 + (ch >> 3), c2 = (ch & 7) * 16;
          int byte = (ws * 128 + c2) ^ ((ws & 7) << 4);
          *(uint4*)(zs + byte) = make_uint4(0, 0, 0, 0);
        }
      }
      if (tid < 16) {
        int ws = (tid < 8) ? 0 : 129; int c2 = (tid & 7) * 16;
        int byte = (ws * 128 + c2) ^ ((ws & 7) << 4);
        *(uint4*)(zs + byte) = make_uint4(0, 0, 0, 0);
      }
      __syncthreads();
      #pragma unroll
      for (int kc = 0; kc < 2; kc++) {
        #pragma unroll
        for (int dw = 0; dw < 3; dw++) {
          int tap = dh * 3 + dw;
          bf16x8 bfr[2];
          #pragma unroll
          for (int nt = 0; nt < 2; nt++) {
            int ws = wv * 32 + nt * 16 + (lane & 15) + dw;
            int byte = (ws * 128 + (kc * 32 + (lane >> 4) * 8) * 2) ^ ((ws & 7) << 4);
            bfr[nt] = *(const bf16x8*)(zs + byte);
          }
          const unsigned short* wbp =
              Wb + ((size_t)(p * 9 + tap) * C) * C + kc * 32 + (lane >> 4) * 8;
          #pragma unroll
          for (int mt = 0; mt < 4; mt++) {
            bf16x8 af = *(const bf16x8*)(wbp + (size_t)(mt * 16 + (lane & 15)) * C);
            acc[mt][0] = __builtin_amdgcn_mfma_f32_16x16x32_bf16(af, bfr[0], acc[mt][0], 0, 0, 0);
            acc[mt][1] = __builtin_amdgcn_mfma_f32_16x16x32_bf16(af, bfr[1], acc[mt][1], 0, 0, 0);
          }
        }
      }
    }
  }
  #pragma unroll
  for (int mt = 0; mt < 4; mt++) {
    #pragma unroll
    for (int nt = 0; nt < 2; nt++) {
      int w = wv * 32 + nt * 16 + (lane & 15);
      #pragma unroll
      for (int r = 0; r < 4; r++) {
        int o = mt * 16 + (lane >> 4) * 4 + r;
        outp[((size_t)(bl * C + o) * H + h) * W + w] = acc[mt][nt][r] + btil[o];
      }
    }
  }
}

// ------------------------------------------------------------- LN statistics
__global__ __launch_bounds__(256) void k_lnstats(const float* __restrict__ outp,
                                                 float* __restrict__ mu,
                                                 float* __restrict__ rstd) {
  int i = blockIdx.x;
  const float4* p = (const float4*)(outp + (size_t)i * HW);
  float s = 0, q = 0;
  for (int t = threadIdx.x; t < HW / 4; t += 256) {
    float4 v = p[t];
    s += (v.x + v.y) + (v.z + v.w);
    q += (v.x * v.x + v.y * v.y) + (v.z * v.z + v.w * v.w);
  }
  #pragma unroll
  for (int o2 = 32; o2; o2 >>= 1) { s += __shfl_down(s, o2); q += __shfl_down(q, o2); }
  __shared__ float rs[4], rq[4];
  if ((threadIdx.x & 63) == 0) { rs[threadIdx.x >> 6] = s; rq[threadIdx.x >> 6] = q; }
  __syncthreads();
  if (threadIdx.x == 0) {
    float S = rs[0] + rs[1] + rs[2] + rs[3];
    float Q = rq[0] + rq[1] + rq[2] + rq[3];
    float m = S * (1.0f / HW);
    float var = Q * (1.0f / HW) - m * m;
    mu[i] = m; rstd[i] = rsqrtf(var + 1e-5f);
  }
}

// -------------------------------- gate matmul + LN apply + residual (inplace)
__global__ __launch_bounds__(256) void k_final(const float* __restrict__ x,
                                               const float* __restrict__ gw,
                                               const float* __restrict__ gb,
                                               const float* __restrict__ mu,
                                               const float* __restrict__ rstd,
                                               const float* __restrict__ lnw,
                                               const float* __restrict__ lnb,
                                               float* __restrict__ outp) {
  int bl = blockIdx.x >> 6, h = blockIdx.x & 63;
  int tid = threadIdx.x;
  __shared__ float xs[C * W];   // 32KB
  for (int i = tid; i < C * W; i += 256) {
    int c = i >> 7, w = i & 127;
    xs[i] = x[((size_t)(bl * C + c) * H + h) * W + w];
  }
  __syncthreads();
  int w = tid & 127;
  int oh = __builtin_amdgcn_readfirstlane(tid >> 7);  // wave-uniform 0/1
  float glin[32];
  #pragma unroll
  for (int i = 0; i < 32; i++) glin[i] = gb[oh * 32 + i];
  for (int cc = 0; cc < C; cc++) {
    float xv = xs[cc * W + w];
    const float* gwp = gw + (size_t)(oh * 32) * C + cc;
    #pragma unroll
    for (int i = 0; i < 32; i++) glin[i] += gwp[(size_t)i * C] * xv;
  }
  float lw = lnw[h * W + w], lb = lnb[h * W + w];
  #pragma unroll
  for (int i = 0; i < 32; i++) {
    int o = oh * 32 + i;
    size_t off = ((size_t)(bl * C + o) * H + h) * W + w;
    float m = mu[bl * C + o], rs = rstd[bl * C + o];
    float op = outp[off];
    float nrm = (op - m) * rs * lw + lb;
    float sg = 1.0f / (1.0f + expf(-glin[i]));
    outp[off] = xs[o * W + w] + sg * nrm;
  }
}

// ============================================================================
extern "C" void kernel_launch(void* const* d_in, const int* in_sizes, int n_in,
                              void* d_out, int out_size, void* d_ws,
                              size_t ws_size, hipStream_t stream) {
  const float* x       = (const float*)d_in[0];
  const float* nu_log  = (const float*)d_in[1];
  const float* th_log  = (const float*)d_in[2];
  const float* mlp_w1  = (const float*)d_in[3];
  const float* mlp_b1  = (const float*)d_in[4];
  const float* mlp_w2  = (const float*)d_in[5];
  const float* mlp_b2  = (const float*)d_in[6];
  const float* fscale  = (const float*)d_in[7];
  const float* U_r     = (const float*)d_in[8];
  const float* U_i     = (const float*)d_in[9];
  const float* V_r     = (const float*)d_in[10];
  const float* V_i     = (const float*)d_in[11];
  const float* pW_r    = (const float*)d_in[12];
  const float* pW_i    = (const float*)d_in[13];
  const float* pb_r    = (const float*)d_in[14];
  const float* pb_i    = (const float*)d_in[15];
  const float* swr1    = (const float*)d_in[16];
  const float* swi1    = (const float*)d_in[17];
  const float* swr2    = (const float*)d_in[18];
  const float* swi2    = (const float*)d_in[19];
  const float* convr_w = (const float*)d_in[20];
  const float* convr_b = (const float*)d_in[21];
  const float* convi_w = (const float*)d_in[22];
  const float* convi_b = (const float*)d_in[23];
  const float* fuse_w  = (const float*)d_in[24];
  const float* fuse_b  = (const float*)d_in[25];
  const float* gate_w  = (const float*)d_in[26];
  const float* gate_b  = (const float*)d_in[27];
  const float* ln_w    = (const float*)d_in[28];
  const float* ln_b    = (const float*)d_in[29];
  float* outp = (float*)d_out;

  char* wsb = (char*)d_ws;
  size_t off = 0;
  auto alloc = [&](size_t nbytes) -> void* {
    void* p = (void*)(wsb + off);
    off += ((nbytes + 255) / 256) * 256;
    return p;
  };
  float* trig64  = (float*)alloc(128 * 4);
  float* trig128 = (float*)alloc(256 * 4);
  unsigned short* Ehat = (unsigned short*)alloc(32 * 64 * 2);
  float* Uhat = (float*)alloc((size_t)C * H * R * 2 * 4);
  float* Util = (float*)alloc((size_t)C * H * R * 2 * 4);
  unsigned short* Vhb = (unsigned short*)alloc((size_t)C * 64 * 128 * 2);
  unsigned short* Vt2r = (unsigned short*)alloc((size_t)C * W * R * 2);
  unsigned short* Vt2i = (unsigned short*)alloc((size_t)C * W * R * 2);
  unsigned short* Wb = (unsigned short*)alloc((size_t)2 * 9 * C * C * 2);
  float* btil = (float*)alloc(C * 4);
  unsigned short* P2 = (unsigned short*)alloc((size_t)2 * C * 128 * 2);
  float* ctx  = (float*)alloc(BL * C * 4);
  float* lamr = (float*)alloc(BL * CR * 4);
  float* lami = (float*)alloc(BL * CR * 4);
  float* gam  = (float*)alloc(BL * CR * 4);
  float* ub   = (float*)alloc((size_t)BL * CR * 2 * 4);
  float* hs   = (float*)alloc((size_t)BL * CR * 2 * 4);
  float* Xm   = (float*)alloc((size_t)BL * C * 128 * 2 * 4);
  float* SPm  = (float*)alloc((size_t)BL * C * 128 * 2 * 4);
  float* Qb   = (float*)alloc((size_t)BL * C * H * 8 * 2 * 4);
  unsigned* y2 = (unsigned*)alloc((size_t)BL * HW * C * 4);
  unsigned short* Zr = (unsigned short*)alloc((size_t)BL * HW * C * 2);
  unsigned short* Zi = (unsigned short*)alloc((size_t)BL * HW * C * 2);
  float* mu   = (float*)alloc(BL * C * 4);
  float* rstd = (float*)alloc(BL * C * 4);

  k_trig<<<1, 128, 0, stream>>>(trig64, trig128, Ehat);
  k_utab<<<C, 256, 0, stream>>>(U_r, U_i, trig64, Uhat, Util);
  k_vtab<<<C, 256, 0, stream>>>(V_r, V_i, trig128, Vhb, Vt2r, Vt2i);
  k_wb<<<2 * C, 256, 0, stream>>>(fuse_w, convr_w, convi_w, Wb);
  k_btil<<<1, 64, 0, stream>>>(fuse_w, convr_b, convi_b, fuse_b, btil);
  k_p2<<<C, 128, 0, stream>>>(pW_r, pW_i, P2);
  k_encode<<<BL * C, 256, 0, stream>>>(x, Vhb, Uhat, Ehat, trig128, ub, Xm, ctx);
  k_mlp<<<BL, 256, 0, stream>>>(ctx, mlp_w1, mlp_b1, mlp_w2, mlp_b2, fscale,
                                nu_log, th_log, lamr, lami, gam);
  k_scan<<<16, 256, 0, stream>>>(lamr, lami, gam, ub, hs);
  k_spm<<<dim3(BL, 8), 256, 0, stream>>>(Xm, swr1, swi1, swr2, swi2, SPm);
  k_q<<<BL * C, 256, 0, stream>>>(SPm, trig64, Qb);
  k_y<<<dim3(BL, 4, 32), 256, 0, stream>>>(hs, Util, Vt2r, Vt2i, y2);
  k_proj<<<dim3(BL, H), 256, 0, stream>>>(y2, P2, Qb, pb_r, pb_i, trig128,
                                          Zr, Zi);
  k_conv<<<BL * H, 256, 0, stream>>>(Zr, Zi, Wb, btil, outp);
  k_lnstats<<<BL * C, 256, 0, stream>>>(outp, mu, rstd);
  k_final<<<BL * H, 256, 0, stream>>>(x, gate_w, gate_b, mu, rstd, ln_w, ln_b,
                                      outp);
}

// Round 9
// 851.899 us; speedup vs baseline: 2.8439x; 1.0344x over previous
//
#include <hip/hip_runtime.h>
#include <math.h>

// ============================================================================
// ConvLRUBlock on MI355X — round 8 (resubmit after infra timeout): k_conv
// coalesced staging + double-buffered single-barrier pipeline; k_y/k_proj y2
// layout [chunk][pix] for coalesced writes. MFMA encode (+ctx fused), MFMA
// decode, MFMA implicit-GEMM conv.
// ============================================================================

constexpr int B_ = 2, L_ = 16, C = 64, H = 64, W = 128, R = 32, MH = 32;
constexpr int BL = B_ * L_;     // 32
constexpr int HW = H * W;       // 8192
constexpr int CR = C * R;       // 2048
constexpr float PI2 = 6.28318530717958647692f;

#define DEV __device__ __forceinline__

typedef __attribute__((ext_vector_type(8))) short bf16x8;
typedef __attribute__((ext_vector_type(4))) float f32x4;

static DEV unsigned short f2bf(float f) {
  unsigned u = __float_as_uint(f);
  u = u + 0x7fffu + ((u >> 16) & 1u);
  return (unsigned short)(u >> 16);
}

// -------------------------------------------- trig tables + DFT-coeff A-frags
__global__ __launch_bounds__(128) void k_trig(float* __restrict__ t64,
                                              float* __restrict__ t128,
                                              unsigned short* __restrict__ Ehat) {
  int i = threadIdx.x;
  if (i < 64) {
    float s, c; sincosf(PI2 * (float)i / 64.0f, &s, &c);
    t64[2 * i] = c; t64[2 * i + 1] = s;
  }
  float s, c; sincosf(PI2 * (float)i / 128.0f, &s, &c);
  t128[2 * i] = c; t128[2 * i + 1] = s;
  for (int j = 0; j < 16; j++) {
    int idx = j * 128 + i;              // 0..2047
    int row = idx >> 6, hh = idx & 63;
    int i1 = row & 15, p = row >> 4;
    int m1 = i1 < 8 ? i1 : 48 + i1;
    float ang = PI2 * (float)((m1 * hh) & 63) / 64.0f;
    float s2, c2; sincosf(ang, &s2, &c2);
    Ehat[row * 64 + hh] = f2bf(p ? -s2 : c2);
  }
}

// ------------------------------------------------- U tables: fwd DFT, inv DFT
__global__ __launch_bounds__(256) void k_utab(const float* __restrict__ Ur,
                                              const float* __restrict__ Ui,
                                              const float* __restrict__ t64,
                                              float* __restrict__ Uhat,
                                              float* __restrict__ Util) {
  int c = blockIdx.x;
  __shared__ float tt[128];
  if (threadIdx.x < 128) tt[threadIdx.x] = t64[threadIdx.x];
  __syncthreads();
  for (int t = 0; t < 8; t++) {
    int idx = t * 256 + threadIdx.x;
    int hp = idx >> 5, r = idx & 31;
    float fr = 0, fi = 0, br = 0, bi = 0;
    for (int h = 0; h < H; h++) {
      float ur = Ur[(c * H + h) * R + r], ui = Ui[(c * H + h) * R + r];
      int ph = (h * hp) & 63;
      float cs = tt[2 * ph], sn = tt[2 * ph + 1];
      fr += ur * cs + ui * sn;
      fi += ui * cs - ur * sn;
      br += ur * cs - ui * sn;
      bi += ui * cs + ur * sn;
    }
    int o = ((c * H + hp) * R + r) * 2;
    Uhat[o] = fr; Uhat[o + 1] = fi;
    Util[o] = br * (1.0f / H); Util[o + 1] = bi * (1.0f / H);
  }
}

// Vhb[c][2r+comp][w] bf16 (fwd DFT, B-operand for encode GEMM1);
// Vt2r/Vt2i[c][wp][r] bf16 (inv, 1/W — for k_y)
__global__ __launch_bounds__(256) void k_vtab(const float* __restrict__ Vr,
                                              const float* __restrict__ Vi,
                                              const float* __restrict__ t128,
                                              unsigned short* __restrict__ Vhb,
                                              unsigned short* __restrict__ Vt2r,
                                              unsigned short* __restrict__ Vt2i) {
  int c = blockIdx.x;
  __shared__ float tt[256];
  tt[threadIdx.x] = t128[threadIdx.x];
  __syncthreads();
  for (int t = 0; t < 16; t++) {
    int idx = t * 256 + threadIdx.x;
    int wp = idx >> 5, r = idx & 31;
    float fr = 0, fi = 0, br = 0, bi = 0;
    for (int w = 0; w < W; w++) {
      float vr = Vr[(c * W + w) * R + r], vi = Vi[(c * W + w) * R + r];
      int ph = (w * wp) & 127;
      float cs = tt[2 * ph], sn = tt[2 * ph + 1];
      fr += vr * cs + vi * sn;
      fi += vi * cs - vr * sn;
      br += vr * cs - vi * sn;
      bi += vi * cs + vr * sn;
    }
    Vhb[((size_t)c * 64 + 2 * r) * 128 + wp] = f2bf(fr);
    Vhb[((size_t)c * 64 + 2 * r + 1) * 128 + wp] = f2bf(fi);
    Vt2r[(size_t)(c * W + wp) * R + r] = f2bf(br * (1.0f / W));
    Vt2i[(size_t)(c * W + wp) * R + r] = f2bf(bi * (1.0f / W));
  }
}

// ---------------- fold fuse_w into conv weights, MFMA A-frag order, bf16
__global__ __launch_bounds__(256) void k_wb(const float* __restrict__ fuse_w,
                                            const float* __restrict__ convr_w,
                                            const float* __restrict__ convi_w,
                                            unsigned short* __restrict__ Wb) {
  int po = blockIdx.x; int p = po >> 6, o = po & 63;
  const float* cw = p ? convi_w : convr_w;
  __shared__ float fw[64];
  if (threadIdx.x < 64) fw[threadIdx.x] = fuse_w[o * (2 * C) + p * C + threadIdx.x];
  __syncthreads();
  for (int t = 0; t < 3; t++) {
    int idx = t * 256 + threadIdx.x;      // tap*64 + c
    if (idx < 576) {
      int tap = idx >> 6, c = idx & 63;
      float s = 0;
      for (int k = 0; k < C; k++) s += fw[k] * cw[(k * C + c) * 9 + tap];
      Wb[((size_t)(p * 9 + tap) * C + o) * C + c] = f2bf(s);
    }
  }
}

__global__ __launch_bounds__(64) void k_btil(const float* __restrict__ fuse_w,
                                             const float* __restrict__ rb,
                                             const float* __restrict__ ib,
                                             const float* __restrict__ fb,
                                             float* __restrict__ btil) {
  int o = threadIdx.x;
  float s = fb[o];
  for (int k = 0; k < C; k++)
    s += fuse_w[o * (2 * C) + k] * rb[k] + fuse_w[o * (2 * C) + C + k] * ib[k];
  btil[o] = s;
}

// --------------- P2: interleaved complex proj weights, bf16, pre-swizzled
__global__ __launch_bounds__(128) void k_p2(const float* __restrict__ pwr,
                                            const float* __restrict__ pwi,
                                            unsigned short* __restrict__ P2) {
  int o = blockIdx.x;
  int k = threadIdx.x;           // 0..127
  int c = k >> 1, odd = k & 1;
  float pr = pwr[o * C + c], pi = pwi[o * C + c];
  float vr = odd ? -pi : pr;
  float vi = odd ? pr : pi;
  int boff = (k * 2) ^ ((o & 7) << 4);
  *(unsigned short*)((char*)P2 + o * 256 + boff) = f2bf(vr);
  *(unsigned short*)((char*)P2 + 16384 + o * 256 + boff) = f2bf(vi);
}

// --------------------------------------------- MLP forcing -> lam, gamma
__global__ __launch_bounds__(256) void k_mlp(const float* __restrict__ ctx,
                                             const float* __restrict__ w1,
                                             const float* __restrict__ b1,
                                             const float* __restrict__ w2,
                                             const float* __restrict__ b2,
                                             const float* __restrict__ fs_p,
                                             const float* __restrict__ nu_log,
                                             const float* __restrict__ th_log,
                                             float* __restrict__ lamr,
                                             float* __restrict__ lami,
                                             float* __restrict__ gam) {
  int bl = blockIdx.x;
  __shared__ float cs[C];
  __shared__ float hm[MH];
  if (threadIdx.x < C) cs[threadIdx.x] = ctx[bl * C + threadIdx.x];
  __syncthreads();
  if (threadIdx.x < MH) {
    float s = b1[threadIdx.x];
    for (int k = 0; k < C; k++) s += cs[k] * w1[k * MH + threadIdx.x];
    hm[threadIdx.x] = tanhf(s);
  }
  __syncthreads();
  float fs = fs_p[0];
  for (int t = 0; t < 8; t++) {
    int idx = t * 256 + threadIdx.x;       // (c,r) flat over CR
    float d0 = b2[idx], d1 = b2[CR + idx];
    for (int m = 0; m < MH; m++) {
      float hv = hm[m];
      d0 += hv * w2[m * (2 * CR) + idx];
      d1 += hv * w2[m * (2 * CR) + CR + idx];
    }
    float nu = expf(nu_log[idx] + fs * d0);
    float th = expf(th_log[idx] + fs * d1);
    float en = expf(-nu);
    float sn, cn; sincosf(th, &sn, &cn);
    int o = bl * CR + idx;
    lamr[o] = en * cn; lami[o] = en * sn;
    gam[o] = sqrtf(fmaxf(0.0f, 1.0f - en * en));
  }
}

// --------------------------- encode (MFMA): u[b,l,c,r], Xm low modes, ctx
__global__ __launch_bounds__(256) void k_encode(
    const float* __restrict__ x, const unsigned short* __restrict__ Vhb,
    const float* __restrict__ Uhat, const unsigned short* __restrict__ Ehat,
    const float* __restrict__ t128, float* __restrict__ ub,
    float* __restrict__ Xm, float* __restrict__ ctx) {
  int blc = blockIdx.x;
  int c = blc & 63;
  __shared__ __align__(16) char ldsA[16384];   // xb, then s
  __shared__ __align__(16) char ldsB[16384];   // xbt, then Fh
  __shared__ float red[4];
  int tid = threadIdx.x;
  int lane = tid & 63;
  int wv = __builtin_amdgcn_readfirstlane(tid >> 6);
  int col = lane & 15, kg = lane >> 4;

  // ---- stage x -> bf16 xb[h][w] + xbt[w][h]; accumulate ctx sum
  const float4* px4 = (const float4*)(x + (size_t)blc * HW);
  float csum = 0;
  #pragma unroll
  for (int j = 0; j < 8; j++) {
    int e4 = j * 256 + tid;             // float4 index, 2048 total
    float4 v = px4[e4];
    csum += (v.x + v.y) + (v.z + v.w);
    int elem = e4 * 4;
    int h = elem >> 7, w = elem & 127;
    unsigned p0 = (unsigned)f2bf(v.x) | ((unsigned)f2bf(v.y) << 16);
    unsigned p1 = (unsigned)f2bf(v.z) | ((unsigned)f2bf(v.w) << 16);
    int ba = (h * 256 + w * 2) ^ ((h & 7) << 4);
    *(uint2*)(ldsA + ba) = make_uint2(p0, p1);
    unsigned short t0 = f2bf(v.x), t1 = f2bf(v.y), t2 = f2bf(v.z), t3 = f2bf(v.w);
    *(unsigned short*)(ldsB + (((w + 0) * 128 + h * 2) ^ (((w + 0) & 7) << 4))) = t0;
    *(unsigned short*)(ldsB + (((w + 1) * 128 + h * 2) ^ (((w + 1) & 7) << 4))) = t1;
    *(unsigned short*)(ldsB + (((w + 2) * 128 + h * 2) ^ (((w + 2) & 7) << 4))) = t2;
    *(unsigned short*)(ldsB + (((w + 3) * 128 + h * 2) ^ (((w + 3) & 7) << 4))) = t3;
  }
  #pragma unroll
  for (int m = 32; m; m >>= 1) csum += __shfl_xor(csum, m);
  if (lane == 0) red[wv] = csum;
  __syncthreads();
  if (tid == 0)
    ctx[blc] = (red[0] + red[1] + red[2] + red[3]) * (1.0f / HW);

  // ---- GEMM1: s[h][2r+comp] = x @ Vhat   (M=16h/wave, N=64, K=128)
  f32x4 acc1[4];
  #pragma unroll
  for (int nt = 0; nt < 4; nt++) acc1[nt] = (f32x4){0, 0, 0, 0};
  int hA = wv * 16 + col;
  #pragma unroll
  for (int ks = 0; ks < 4; ks++) {
    int k0 = ks * 32 + kg * 8;
    bf16x8 a = *(const bf16x8*)(ldsA + ((hA * 256 + k0 * 2) ^ ((hA & 7) << 4)));
    #pragma unroll
    for (int nt = 0; nt < 4; nt++) {
      int n = nt * 16 + col;
      bf16x8 b = *(const bf16x8*)(Vhb + ((size_t)c * 64 + n) * 128 + k0);
      acc1[nt] = __builtin_amdgcn_mfma_f32_16x16x32_bf16(a, b, acc1[nt], 0, 0, 0);
    }
  }
  // ---- GEMM2: Fh[p*16+i1][w] = Ehat @ x^T  (M=32, N=32w/wave, K=64)
  f32x4 acc2[2][2];
  #pragma unroll
  for (int mt = 0; mt < 2; mt++)
    for (int nt = 0; nt < 2; nt++) acc2[mt][nt] = (f32x4){0, 0, 0, 0};
  #pragma unroll
  for (int ks = 0; ks < 2; ks++) {
    int k0 = ks * 32 + kg * 8;
    bf16x8 a2[2];
    #pragma unroll
    for (int mt = 0; mt < 2; mt++)
      a2[mt] = *(const bf16x8*)(Ehat + (mt * 16 + col) * 64 + k0);
    #pragma unroll
    for (int nt = 0; nt < 2; nt++) {
      int w = wv * 32 + nt * 16 + col;
      bf16x8 b2 = *(const bf16x8*)(ldsB + ((w * 128 + k0 * 2) ^ ((w & 7) << 4)));
      #pragma unroll
      for (int mt = 0; mt < 2; mt++)
        acc2[mt][nt] = __builtin_amdgcn_mfma_f32_16x16x32_bf16(a2[mt], b2, acc2[mt][nt], 0, 0, 0);
    }
  }
  __syncthreads();   // all LDS reads of xb/xbt complete
  // write s (f32 [64][64], swz) into ldsA; Fh (f32 [32][128], swz) into ldsB
  #pragma unroll
  for (int nt = 0; nt < 4; nt++) {
    int r2 = nt * 16 + col;
    #pragma unroll
    for (int j = 0; j < 4; j++) {
      int h = wv * 16 + kg * 4 + j;
      *(float*)(ldsA + ((h * 256 + r2 * 4) ^ ((h & 7) << 4))) = acc1[nt][j];
    }
  }
  #pragma unroll
  for (int mt = 0; mt < 2; mt++)
    for (int nt = 0; nt < 2; nt++)
      #pragma unroll
      for (int j = 0; j < 4; j++) {
        int mrow = mt * 16 + kg * 4 + j;
        int w = wv * 32 + nt * 16 + col;
        *(float*)(ldsB + ((mrow * 512 + w * 4) ^ ((mrow & 7) << 4))) = acc2[mt][nt][j];
      }
  __syncthreads();

  // ---- u[r] = sum_h Uhat[h][r] (cplx) * s[h][r] (cplx)
  {
    int r = tid >> 3, hg = tid & 7;
    float ar = 0, ai = 0;
    #pragma unroll
    for (int j = 0; j < 8; j++) {
      int h = hg + 8 * j;
      float2 sv = *(const float2*)(ldsA + ((h * 256 + r * 8) ^ ((h & 7) << 4)));
      const float* up = Uhat + (((size_t)c * H + h) * R + r) * 2;
      float ur = up[0], ui = up[1];
      ar += ur * sv.x - ui * sv.y;
      ai += ur * sv.y + ui * sv.x;
    }
    ar += __shfl_xor(ar, 1); ai += __shfl_xor(ai, 1);
    ar += __shfl_xor(ar, 2); ai += __shfl_xor(ai, 2);
    ar += __shfl_xor(ar, 4); ai += __shfl_xor(ai, 4);
    if (hg == 0) {
      ub[((size_t)blc * R + r) * 2] = ar;
      ub[((size_t)blc * R + r) * 2 + 1] = ai;
    }
  }
  // ---- Xm[i1][m2] = sum_w Fh[i1][w] * e^{-2pi i m2 w/128}
  {
    int i1 = tid >> 4, m2 = (tid >> 1) & 7, half = tid & 1;
    float ar = 0, ai = 0;
    for (int jw = 0; jw < 64; jw++) {
      int w = half * 64 + jw;
      float fr = *(const float*)(ldsB + ((i1 * 512 + w * 4) ^ ((i1 & 7) << 4)));
      float fi = *(const float*)(ldsB + (((16 + i1) * 512 + w * 4) ^ ((i1 & 7) << 4)));
      int ph = (m2 * w) & 127;
      float cs = t128[2 * ph], sn = t128[2 * ph + 1];
      ar += fr * cs + fi * sn;
      ai += fi * cs - fr * sn;
    }
    ar += __shfl_xor(ar, 1); ai += __shfl_xor(ai, 1);
    if (half == 0) {
      Xm[((size_t)blc * 128 + i1 * 8 + m2) * 2] = ar;
      Xm[((size_t)blc * 128 + i1 * 8 + m2) * 2 + 1] = ai;
    }
  }
}

// ------------------------------------------------- sequential scan over L=16
__global__ __launch_bounds__(256) void k_scan(const float* __restrict__ lamr,
                                              const float* __restrict__ lami,
                                              const float* __restrict__ gam,
                                              const float* __restrict__ ub,
                                              float* __restrict__ hs) {
  int idx = blockIdx.x * 256 + threadIdx.x;   // over B*C*R = 4096
  int b = idx >> 11, cr = idx & 2047;
  float hr = 0, hi = 0;
  for (int l = 0; l < L_; l++) {
    int o = (b * L_ + l) * CR + cr;
    float lr = lamr[o], li = lami[o], g = gam[o];
    float ur = ub[2 * o], ui = ub[2 * o + 1];
    float nr = lr * hr - li * hi + g * ur;
    float ni = lr * hi + li * hr + g * ui;
    hr = nr; hi = ni;
    hs[2 * o] = hr; hs[2 * o + 1] = hi;
  }
}

// ------------------------ spectral conv: mode mix (w1 low rows, w2 high rows)
__global__ __launch_bounds__(256) void k_spm(const float* __restrict__ Xm,
                                             const float* __restrict__ w1r,
                                             const float* __restrict__ w1i,
                                             const float* __restrict__ w2r,
                                             const float* __restrict__ w2i,
                                             float* __restrict__ SPm) {
  int bl = blockIdx.x;
  int o0 = blockIdx.y * 8;
  const float* px = Xm + (size_t)bl * C * 256;
  for (int t = 0; t < 4; t++) {
    int idx = t * 256 + threadIdx.x;      // local o*128 + mode, 1024 items
    int o = o0 + (idx >> 7), mode = idx & 127;
    int i1 = mode >> 3, m2 = mode & 7;
    const float* wr; const float* wi; int ii;
    if (i1 < 8) { wr = w1r; wi = w1i; ii = i1; }
    else        { wr = w2r; wi = w2i; ii = i1 - 8; }
    float ar = 0, ai = 0;
    for (int cc = 0; cc < C; cc++) {
      float xr = px[(cc * 128 + mode) * 2], xi = px[(cc * 128 + mode) * 2 + 1];
      float wrr = wr[((size_t)(o * C + cc) * 8 + ii) * 8 + m2];
      float wii = wi[((size_t)(o * C + cc) * 8 + ii) * 8 + m2];
      ar += xr * wrr - xi * wii;
      ai += xr * wii + xi * wrr;
    }
    size_t oo = (size_t)bl * C * 128 + (size_t)o * 128 + mode;
    SPm[oo * 2] = ar * (1.0f / HW);
    SPm[oo * 2 + 1] = ai * (1.0f / HW);
  }
}

// ---------------- Q[blo][h][m2] = sum_i1 SPm[blo][i1][m2] e^{+2pi i m1 h/64}
__global__ __launch_bounds__(256) void k_q(const float* __restrict__ SPm,
                                           const float* __restrict__ t64,
                                           float* __restrict__ Qb) {
  int blo = blockIdx.x;                 // bl*64 + o
  __shared__ float sp[256];
  int tid = threadIdx.x;
  sp[tid] = SPm[(size_t)blo * 256 + tid];
  __syncthreads();
  for (int t = 0; t < 2; t++) {
    int idx = t * 256 + tid;
    int h = idx >> 3, m2 = idx & 7;
    float ar = 0, ai = 0;
    #pragma unroll
    for (int i1 = 0; i1 < 16; i1++) {
      int m1 = i1 < 8 ? i1 : 48 + i1;
      int ph = (m1 * h) & 63;
      float cs = t64[2 * ph], sn = t64[2 * ph + 1];
      float sr = sp[(i1 * 8 + m2) * 2], si = sp[(i1 * 8 + m2) * 2 + 1];
      ar += sr * cs - si * sn;
      ai += sr * sn + si * cs;
    }
    Qb[((size_t)blo * H * 8 + idx) * 2] = ar;
    Qb[((size_t)blo * H * 8 + idx) * 2 + 1] = ai;
  }
}

// ---------------- k_y: y[bl,c,h,w] = sum_r (hs*Util) * Vtil  via MFMA.
// y2 layout: [chunk(16)][bl*H*W pix][16B (4 c's r,i bf16)] — coalesced writes.
__global__ __launch_bounds__(256) void k_y(
    const float* __restrict__ hs, const float* __restrict__ Util,
    const unsigned short* __restrict__ Vt2r,
    const unsigned short* __restrict__ Vt2i,
    unsigned* __restrict__ y2) {
  int bl = blockIdx.x;
  int h0 = blockIdx.y * 16;
  int zz = blockIdx.z;
  int w0 = (zz >> 4) * 64;
  int chunk = zz & 15;
  int tid = threadIdx.x;
  int lane = tid & 63;
  int wv = __builtin_amdgcn_readfirstlane(tid >> 6);
  __shared__ unsigned ybuf[1024 * 4];   // [pix local 16h*64w][4 c] u32 16KB
  int row = lane & 15;          // A: m(h) / B: n(w) index
  int kg = lane >> 4;           // k-group
  int c = chunk * 4 + wv;
  const float* up = Util + (((size_t)c * H + h0 + row) * R + kg * 8) * 2;
  const float* hp = hs + (((size_t)bl * C + c) * R + kg * 8) * 2;
  bf16x8 aGr, aGi, aGn;
  #pragma unroll
  for (int j = 0; j < 8; j++) {
    float ur = up[2 * j], ui = up[2 * j + 1];
    float hr = hp[2 * j], hi = hp[2 * j + 1];
    float gr = hr * ur - hi * ui, gi = hr * ui + hi * ur;
    aGr[j] = (short)f2bf(gr); aGi[j] = (short)f2bf(gi);
    aGn[j] = (short)f2bf(-gi);
  }
  #pragma unroll
  for (int nt = 0; nt < 4; nt++) {
    int w = w0 + nt * 16 + row;
    const unsigned short* vr = Vt2r + ((size_t)c * W + w) * R + kg * 8;
    const unsigned short* vi = Vt2i + ((size_t)c * W + w) * R + kg * 8;
    bf16x8 bVr = *(const bf16x8*)vr;
    bf16x8 bVi = *(const bf16x8*)vi;
    f32x4 accr = {0, 0, 0, 0}, acci = {0, 0, 0, 0};
    accr = __builtin_amdgcn_mfma_f32_16x16x32_bf16(aGr, bVr, accr, 0, 0, 0);
    accr = __builtin_amdgcn_mfma_f32_16x16x32_bf16(aGn, bVi, accr, 0, 0, 0);
    acci = __builtin_amdgcn_mfma_f32_16x16x32_bf16(aGr, bVi, acci, 0, 0, 0);
    acci = __builtin_amdgcn_mfma_f32_16x16x32_bf16(aGi, bVr, acci, 0, 0, 0);
    #pragma unroll
    for (int r = 0; r < 4; r++) {
      int hl = kg * 4 + r;
      unsigned pk = (unsigned)f2bf(accr[r]) | ((unsigned)f2bf(acci[r]) << 16);
      ybuf[(hl * 64 + nt * 16 + row) * 4 + wv] = pk;
    }
  }
  __syncthreads();
  // gather 16B per pixel (4 c's), write coalesced into chunk-plane
  #pragma unroll
  for (int q = 0; q < 4; q++) {
    int p = q * 256 + tid;              // local pix
    int lh = p >> 6, lw = p & 63;
    uint4 v = *(const uint4*)&ybuf[p * 4];
    size_t pixg = ((size_t)bl * H + h0 + lh) * W + (w0 + lw);
    *(uint4*)((char*)y2 + ((size_t)chunk * BL * HW + pixg) * 16) = v;
  }
}

// ---------------- k_proj: z[o][w] = P * y (complex via real K=128) + Q + b
__global__ __launch_bounds__(256) void k_proj(
    const unsigned* __restrict__ y2, const unsigned short* __restrict__ P2,
    const float* __restrict__ Qb, const float* __restrict__ pbr,
    const float* __restrict__ pbi, const float* __restrict__ t128,
    unsigned short* __restrict__ Zr, unsigned short* __restrict__ Zi) {
  int bl = blockIdx.x;
  int h = blockIdx.y;
  int tid = threadIdx.x, lane = tid & 63;
  int wv = __builtin_amdgcn_readfirstlane(tid >> 6);
  __shared__ __align__(16) char ylds[32768];
  __shared__ __align__(16) char plds[32768];
  // stage y-row: per chunk, 128 contiguous 16B pixels -> swizzled LDS writes
  {
    const char* gyb = (const char*)y2;
    #pragma unroll
    for (int k2 = 0; k2 < 8; k2++) {
      int idx = k2 * 256 + tid;
      int chunk = idx >> 7, w = idx & 127;
      uint4 v = *(const uint4*)(gyb +
          ((size_t)chunk * BL * HW + (size_t)bl * HW + h * W + w) * 16);
      int byte = (w * 256 + chunk * 16) ^ ((w & 7) << 4);
      *(uint4*)(ylds + byte) = v;
    }
    const uint4* gp = (const uint4*)P2;
    uint4* lp = (uint4*)plds;
    for (int i = tid; i < 2048; i += 256) lp[i] = gp[i];
  }
  __syncthreads();
  int col = lane & 15, kg = lane >> 4;
  f32x4 zr[4][2], zi[4][2];
  #pragma unroll
  for (int mt = 0; mt < 4; mt++)
    for (int nt = 0; nt < 2; nt++) { zr[mt][nt] = (f32x4){0,0,0,0}; zi[mt][nt] = (f32x4){0,0,0,0}; }
  #pragma unroll
  for (int ks = 0; ks < 4; ks++) {
    int koff = ks * 64 + kg * 16;
    bf16x8 ar[4], ai[4];
    #pragma unroll
    for (int mt = 0; mt < 4; mt++) {
      int o = mt * 16 + col;
      int ab = o * 256 + (koff ^ ((o & 7) << 4));
      ar[mt] = *(const bf16x8*)(plds + ab);
      ai[mt] = *(const bf16x8*)(plds + 16384 + ab);
    }
    #pragma unroll
    for (int nt = 0; nt < 2; nt++) {
      int pix = wv * 32 + nt * 16 + col;
      bf16x8 b = *(const bf16x8*)(ylds + pix * 256 + (koff ^ ((pix & 7) << 4)));
      #pragma unroll
      for (int mt = 0; mt < 4; mt++) {
        zr[mt][nt] = __builtin_amdgcn_mfma_f32_16x16x32_bf16(ar[mt], b, zr[mt][nt], 0, 0, 0);
        zi[mt][nt] = __builtin_amdgcn_mfma_f32_16x16x32_bf16(ai[mt], b, zi[mt][nt], 0, 0, 0);
      }
    }
  }
  #pragma unroll
  for (int nt = 0; nt < 2; nt++) {
    int w = wv * 32 + nt * 16 + col;
    float csv[8], snv[8];
    #pragma unroll
    for (int m2 = 0; m2 < 8; m2++) {
      int ph = (m2 * w) & 127;
      csv[m2] = t128[2 * ph]; snv[m2] = t128[2 * ph + 1];
    }
    #pragma unroll
    for (int mt = 0; mt < 4; mt++) {
      float vrr[4], vii[4];
      #pragma unroll
      for (int r = 0; r < 4; r++) {
        int o = mt * 16 + kg * 4 + r;
        const float* qp = Qb + ((size_t)(bl * C + o) * H + h) * 16;
        float vr = zr[mt][nt][r], vi = zi[mt][nt][r];
        #pragma unroll
        for (int m2 = 0; m2 < 8; m2++) {
          float qr = qp[2 * m2], qi = qp[2 * m2 + 1];
          vr += qr * csv[m2] - qi * snv[m2];
          vi += qr * snv[m2] + qi * csv[m2];
        }
        if (h == 0 && w == 0) { vr += pbr[o]; vi += pbi[o]; }
        vrr[r] = vr; vii[r] = vi;
      }
      size_t zoff = (((size_t)bl * H + h) * W + w) * C + mt * 16 + kg * 4;
      unsigned p0 = f2bf(vrr[0]) | ((unsigned)f2bf(vrr[1]) << 16);
      unsigned p1 = f2bf(vrr[2]) | ((unsigned)f2bf(vrr[3]) << 16);
      *(uint2*)(Zr + zoff) = make_uint2(p0, p1);
      unsigned q0 = f2bf(vii[0]) | ((unsigned)f2bf(vii[1]) << 16);
      unsigned q1 = f2bf(vii[2]) | ((unsigned)f2bf(vii[3]) << 16);
      *(uint2*)(Zi + zoff) = make_uint2(q0, q1);
    }
  }
}

// ------------------ MFMA implicit-GEMM 3x3 conv (both planes) -> out_pre
// Double-buffered LDS, coalesced reg-staging, one barrier per stage.
__global__ __launch_bounds__(256) void k_conv(const unsigned short* __restrict__ Zr,
                                              const unsigned short* __restrict__ Zi,
                                              const unsigned short* __restrict__ Wb,
                                              const float* __restrict__ btil,
                                              float* __restrict__ outp) {
  int bl = blockIdx.x >> 6;
  int h = blockIdx.x & 63;
  int tid = threadIdx.x;
  int lane = tid & 63;
  int wv = __builtin_amdgcn_readfirstlane(tid >> 6);
  __shared__ __align__(16) char zs[2][130 * 128];   // 2 x [ws(130)][c(64)] bf16 swz
  f32x4 acc[4][2];
  #pragma unroll
  for (int mt = 0; mt < 4; mt++)
    for (int nt = 0; nt < 2; nt++) acc[mt][nt] = (f32x4){0, 0, 0, 0};

  // zero halo columns of both buffers (never overwritten by staging)
  if (tid < 32) {
    int b = tid >> 4, hws = (tid >> 3) & 1, cch = tid & 7;
    int ws = hws ? 129 : 0;
    int byte = (ws * 128 + cch * 16) ^ ((ws & 7) << 4);
    *(uint4*)(zs[b] + byte) = make_uint4(0, 0, 0, 0);
  }

  auto ldrow = [&](int s, uint4* v) {
    int p = s >= 3 ? 1 : 0, dh = s - p * 3;
    int hr = h + dh - 1;
    if (hr >= 0 && hr < H) {
      const uint4* src = (const uint4*)((p ? Zi : Zr) +
                                        ((size_t)(bl * H + hr)) * W * C);
      #pragma unroll
      for (int i = 0; i < 4; i++) v[i] = src[i * 256 + tid];   // coalesced 1KB/instr
    } else {
      #pragma unroll
      for (int i = 0; i < 4; i++) v[i] = make_uint4(0, 0, 0, 0);
    }
  };
  auto wrrow = [&](char* buf, const uint4* v) {
    #pragma unroll
    for (int i = 0; i < 4; i++) {
      int ch = i * 256 + tid;
      int ws = 1 + (ch >> 3), c2 = (ch & 7) * 16;
      int byte = (ws * 128 + c2) ^ ((ws & 7) << 4);
      *(uint4*)(buf + byte) = v[i];
    }
  };

  uint4 v[4];
  ldrow(0, v);
  wrrow(zs[0], v);
  #pragma unroll
  for (int s = 0; s < 6; s++) {
    int cur = s & 1;
    if (s < 5) ldrow(s + 1, v);        // issue next stage's loads early
    __syncthreads();                   // zs[cur] writes (and halos) visible
    int p = s >= 3 ? 1 : 0, dh = s - p * 3;
    #pragma unroll
    for (int kc = 0; kc < 2; kc++) {
      #pragma unroll
      for (int dw = 0; dw < 3; dw++) {
        int tap = dh * 3 + dw;
        bf16x8 bfr[2];
        #pragma unroll
        for (int nt = 0; nt < 2; nt++) {
          int ws = wv * 32 + nt * 16 + (lane & 15) + dw;
          int byte = (ws * 128 + (kc * 32 + (lane >> 4) * 8) * 2) ^ ((ws & 7) << 4);
          bfr[nt] = *(const bf16x8*)(zs[cur] + byte);
        }
        const unsigned short* wbp =
            Wb + ((size_t)(p * 9 + tap) * C) * C + kc * 32 + (lane >> 4) * 8;
        #pragma unroll
        for (int mt = 0; mt < 4; mt++) {
          bf16x8 af = *(const bf16x8*)(wbp + (size_t)(mt * 16 + (lane & 15)) * C);
          acc[mt][0] = __builtin_amdgcn_mfma_f32_16x16x32_bf16(af, bfr[0], acc[mt][0], 0, 0, 0);
          acc[mt][1] = __builtin_amdgcn_mfma_f32_16x16x32_bf16(af, bfr[1], acc[mt][1], 0, 0, 0);
        }
      }
    }
    // safe: all waves passed this stage's barrier => stage s-1 reads of
    // zs[cur^1] are complete; write next stage's data into it.
    if (s < 5) wrrow(zs[cur ^ 1], v);
  }
  #pragma unroll
  for (int mt = 0; mt < 4; mt++) {
    #pragma unroll
    for (int nt = 0; nt < 2; nt++) {
      int w = wv * 32 + nt * 16 + (lane & 15);
      #pragma unroll
      for (int r = 0; r < 4; r++) {
        int o = mt * 16 + (lane >> 4) * 4 + r;
        outp[((size_t)(bl * C + o) * H + h) * W + w] = acc[mt][nt][r] + btil[o];
      }
    }
  }
}

// ------------------------------------------------------------- LN statistics
__global__ __launch_bounds__(256) void k_lnstats(const float* __restrict__ outp,
                                                 float* __restrict__ mu,
                                                 float* __restrict__ rstd) {
  int i = blockIdx.x;
  const float4* p = (const float4*)(outp + (size_t)i * HW);
  float s = 0, q = 0;
  for (int t = threadIdx.x; t < HW / 4; t += 256) {
    float4 v = p[t];
    s += (v.x + v.y) + (v.z + v.w);
    q += (v.x * v.x + v.y * v.y) + (v.z * v.z + v.w * v.w);
  }
  #pragma unroll
  for (int o2 = 32; o2; o2 >>= 1) { s += __shfl_down(s, o2); q += __shfl_down(q, o2); }
  __shared__ float rs[4], rq[4];
  if ((threadIdx.x & 63) == 0) { rs[threadIdx.x >> 6] = s; rq[threadIdx.x >> 6] = q; }
  __syncthreads();
  if (threadIdx.x == 0) {
    float S = rs[0] + rs[1] + rs[2] + rs[3];
    float Q = rq[0] + rq[1] + rq[2] + rq[3];
    float m = S * (1.0f / HW);
    float var = Q * (1.0f / HW) - m * m;
    mu[i] = m; rstd[i] = rsqrtf(var + 1e-5f);
  }
}

// -------------------------------- gate matmul + LN apply + residual (inplace)
__global__ __launch_bounds__(256) void k_final(const float* __restrict__ x,
                                               const float* __restrict__ gw,
                                               const float* __restrict__ gb,
                                               const float* __restrict__ mu,
                                               const float* __restrict__ rstd,
                                               const float* __restrict__ lnw,
                                               const float* __restrict__ lnb,
                                               float* __restrict__ outp) {
  int bl = blockIdx.x >> 6, h = blockIdx.x & 63;
  int tid = threadIdx.x;
  __shared__ float xs[C * W];   // 32KB
  for (int i = tid; i < C * W; i += 256) {
    int c = i >> 7, w = i & 127;
    xs[i] = x[((size_t)(bl * C + c) * H + h) * W + w];
  }
  __syncthreads();
  int w = tid & 127;
  int oh = __builtin_amdgcn_readfirstlane(tid >> 7);  // wave-uniform 0/1
  float glin[32];
  #pragma unroll
  for (int i = 0; i < 32; i++) glin[i] = gb[oh * 32 + i];
  for (int cc = 0; cc < C; cc++) {
    float xv = xs[cc * W + w];
    const float* gwp = gw + (size_t)(oh * 32) * C + cc;
    #pragma unroll
    for (int i = 0; i < 32; i++) glin[i] += gwp[(size_t)i * C] * xv;
  }
  float lw = lnw[h * W + w], lb = lnb[h * W + w];
  #pragma unroll
  for (int i = 0; i < 32; i++) {
    int o = oh * 32 + i;
    size_t off = ((size_t)(bl * C + o) * H + h) * W + w;
    float m = mu[bl * C + o], rs = rstd[bl * C + o];
    float op = outp[off];
    float nrm = (op - m) * rs * lw + lb;
    float sg = 1.0f / (1.0f + expf(-glin[i]));
    outp[off] = xs[o * W + w] + sg * nrm;
  }
}

// ============================================================================
extern "C" void kernel_launch(void* const* d_in, const int* in_sizes, int n_in,
                              void* d_out, int out_size, void* d_ws,
                              size_t ws_size, hipStream_t stream) {
  const float* x       = (const float*)d_in[0];
  const float* nu_log  = (const float*)d_in[1];
  const float* th_log  = (const float*)d_in[2];
  const float* mlp_w1  = (const float*)d_in[3];
  const float* mlp_b1  = (const float*)d_in[4];
  const float* mlp_w2  = (const float*)d_in[5];
  const float* mlp_b2  = (const float*)d_in[6];
  const float* fscale  = (const float*)d_in[7];
  const float* U_r     = (const float*)d_in[8];
  const float* U_i     = (const float*)d_in[9];
  const float* V_r     = (const float*)d_in[10];
  const float* V_i     = (const float*)d_in[11];
  const float* pW_r    = (const float*)d_in[12];
  const float* pW_i    = (const float*)d_in[13];
  const float* pb_r    = (const float*)d_in[14];
  const float* pb_i    = (const float*)d_in[15];
  const float* swr1    = (const float*)d_in[16];
  const float* swi1    = (const float*)d_in[17];
  const float* swr2    = (const float*)d_in[18];
  const float* swi2    = (const float*)d_in[19];
  const float* convr_w = (const float*)d_in[20];
  const float* convr_b = (const float*)d_in[21];
  const float* convi_w = (const float*)d_in[22];
  const float* convi_b = (const float*)d_in[23];
  const float* fuse_w  = (const float*)d_in[24];
  const float* fuse_b  = (const float*)d_in[25];
  const float* gate_w  = (const float*)d_in[26];
  const float* gate_b  = (const float*)d_in[27];
  const float* ln_w    = (const float*)d_in[28];
  const float* ln_b    = (const float*)d_in[29];
  float* outp = (float*)d_out;

  char* wsb = (char*)d_ws;
  size_t off = 0;
  auto alloc = [&](size_t nbytes) -> void* {
    void* p = (void*)(wsb + off);
    off += ((nbytes + 255) / 256) * 256;
    return p;
  };
  float* trig64  = (float*)alloc(128 * 4);
  float* trig128 = (float*)alloc(256 * 4);
  unsigned short* Ehat = (unsigned short*)alloc(32 * 64 * 2);
  float* Uhat = (float*)alloc((size_t)C * H * R * 2 * 4);
  float* Util = (float*)alloc((size_t)C * H * R * 2 * 4);
  unsigned short* Vhb = (unsigned short*)alloc((size_t)C * 64 * 128 * 2);
  unsigned short* Vt2r = (unsigned short*)alloc((size_t)C * W * R * 2);
  unsigned short* Vt2i = (unsigned short*)alloc((size_t)C * W * R * 2);
  unsigned short* Wb = (unsigned short*)alloc((size_t)2 * 9 * C * C * 2);
  float* btil = (float*)alloc(C * 4);
  unsigned short* P2 = (unsigned short*)alloc((size_t)2 * C * 128 * 2);
  float* ctx  = (float*)alloc(BL * C * 4);
  float* lamr = (float*)alloc(BL * CR * 4);
  float* lami = (float*)alloc(BL * CR * 4);
  float* gam  = (float*)alloc(BL * CR * 4);
  float* ub   = (float*)alloc((size_t)BL * CR * 2 * 4);
  float* hs   = (float*)alloc((size_t)BL * CR * 2 * 4);
  float* Xm   = (float*)alloc((size_t)BL * C * 128 * 2 * 4);
  float* SPm  = (float*)alloc((size_t)BL * C * 128 * 2 * 4);
  float* Qb   = (float*)alloc((size_t)BL * C * H * 8 * 2 * 4);
  unsigned* y2 = (unsigned*)alloc((size_t)BL * HW * C * 4);
  unsigned short* Zr = (unsigned short*)alloc((size_t)BL * HW * C * 2);
  unsigned short* Zi = (unsigned short*)alloc((size_t)BL * HW * C * 2);
  float* mu   = (float*)alloc(BL * C * 4);
  float* rstd = (float*)alloc(BL * C * 4);

  k_trig<<<1, 128, 0, stream>>>(trig64, trig128, Ehat);
  k_utab<<<C, 256, 0, stream>>>(U_r, U_i, trig64, Uhat, Util);
  k_vtab<<<C, 256, 0, stream>>>(V_r, V_i, trig128, Vhb, Vt2r, Vt2i);
  k_wb<<<2 * C, 256, 0, stream>>>(fuse_w, convr_w, convi_w, Wb);
  k_btil<<<1, 64, 0, stream>>>(fuse_w, convr_b, convi_b, fuse_b, btil);
  k_p2<<<C, 128, 0, stream>>>(pW_r, pW_i, P2);
  k_encode<<<BL * C, 256, 0, stream>>>(x, Vhb, Uhat, Ehat, trig128, ub, Xm, ctx);
  k_mlp<<<BL, 256, 0, stream>>>(ctx, mlp_w1, mlp_b1, mlp_w2, mlp_b2, fscale,
                                nu_log, th_log, lamr, lami, gam);
  k_scan<<<16, 256, 0, stream>>>(lamr, lami, gam, ub, hs);
  k_spm<<<dim3(BL, 8), 256, 0, stream>>>(Xm, swr1, swi1, swr2, swi2, SPm);
  k_q<<<BL * C, 256, 0, stream>>>(SPm, trig64, Qb);
  k_y<<<dim3(BL, 4, 32), 256, 0, stream>>>(hs, Util, Vt2r, Vt2i, y2);
  k_proj<<<dim3(BL, H), 256, 0, stream>>>(y2, P2, Qb, pb_r, pb_i, trig128,
                                          Zr, Zi);
  k_conv<<<BL * H, 256, 0, stream>>>(Zr, Zi, Wb, btil, outp);
  k_lnstats<<<BL * C, 256, 0, stream>>>(outp, mu, rstd);
  k_final<<<BL * H, 256, 0, stream>>>(x, gate_w, gate_b, mu, rstd, ln_w, ln_b,
                                      outp);
}